// Round 10
// baseline (389.432 us; speedup 1.0000x reference)
//
#include <hip/hip_runtime.h>
#include <stdint.h>

#define DIM   2048
#define NSLOT 64
#define MDIM  512
#define TINV  10.0f

typedef __attribute__((ext_vector_type(4))) float     f32x4;
typedef __attribute__((ext_vector_type(8))) _Float16  half8;

#define MFMA16(a,b,c) __builtin_amdgcn_mfma_f32_16x16x32_f16((a),(b),(c),0,0,0)

// ---------------------------------------------------------------------------
// ws layout (bytes), total ~1.59 MB:
//   W2F  [16ch][5t][4ks][2lvl][64lane][8] f16  (1.31 MB, fragment-packed W2)
//        row r = t*16 + (lane&15); k = ch*128 + ks*32 + (lane>>4)*8 + e
//        lvl 0 = fp16 hi of (memory@key_w | gate_w row 64 | 0), lvl 1 = residual
//   W3T  [2048][64] f16 : W3T[d][n] = sum_m memory[n][m]*value_w[d][m]
//   h    [64] f32       : h[n] = sum_d W3[n][d]*gate_w[DIM+d]
//   tpart[8][512] f32
// ---------------------------------------------------------------------------
#define OFF_W2F   0
#define OFF_W3T   1310720
#define OFF_H     1572864
#define OFF_TPART 1573120

__device__ __forceinline__ size_t w2f_idx(int row, int k, int lvl) {
    const int t  = row >> 4, ar = row & 15;
    const int ch = k >> 7, ks = (k >> 5) & 3, kg = (k >> 3) & 3, e = k & 7;
    return ((size_t)((((ch * 5 + t) * 4 + ks) * 2 + lvl) * 64) + kg * 16 + ar) * 8 + e;
}

// ============================ prep kernels =================================

__global__ __launch_bounds__(256) void prep_w2(
    const float* __restrict__ memory, const float* __restrict__ key_w,
    const float* __restrict__ gate_w, _Float16* __restrict__ W2F)
{
    const int tid = threadIdx.x;
    const int c = blockIdx.x;      // k-chunk of 256
    const int g = blockIdx.y;      // 0..7 slot groups, 8 = gate row + zero rows
    const int k = c * 256 + tid;

    if (g == 8) {
        float v = gate_w[k];
        _Float16 ph = (_Float16)v;
        _Float16 pl = (_Float16)(v - (float)ph);
        W2F[w2f_idx(64, k, 0)] = ph;
        W2F[w2f_idx(64, k, 1)] = pl;
        for (int r = 65; r < 80; ++r) {
            W2F[w2f_idx(r, k, 0)] = (_Float16)0.f;
            W2F[w2f_idx(r, k, 1)] = (_Float16)0.f;
        }
        return;
    }

    __shared__ __align__(16) float mem_s[8 * MDIM];
    for (int i = tid; i < 8 * MDIM; i += 256)
        mem_s[i] = memory[g * 8 * MDIM + i];
    __syncthreads();

    const f32x4* ms4 = (const f32x4*)mem_s;
    float acc[8] = {};
    for (int m4 = 0; m4 < MDIM / 4; ++m4) {
        const float kw0 = key_w[(size_t)(m4 * 4 + 0) * DIM + k];
        const float kw1 = key_w[(size_t)(m4 * 4 + 1) * DIM + k];
        const float kw2 = key_w[(size_t)(m4 * 4 + 2) * DIM + k];
        const float kw3 = key_w[(size_t)(m4 * 4 + 3) * DIM + k];
        #pragma unroll
        for (int i = 0; i < 8; ++i) {
            const f32x4 mv = ms4[i * (MDIM / 4) + m4];
            acc[i] = fmaf(mv.x, kw0, acc[i]);
            acc[i] = fmaf(mv.y, kw1, acc[i]);
            acc[i] = fmaf(mv.z, kw2, acc[i]);
            acc[i] = fmaf(mv.w, kw3, acc[i]);
        }
    }
    #pragma unroll
    for (int i = 0; i < 8; ++i) {
        float v = acc[i];
        _Float16 ph = (_Float16)v;
        _Float16 pl = (_Float16)(v - (float)ph);
        W2F[w2f_idx(g * 8 + i, k, 0)] = ph;
        W2F[w2f_idx(g * 8 + i, k, 1)] = pl;
    }
}

__global__ __launch_bounds__(256) void prep_w3t(
    const float* __restrict__ memory, const float* __restrict__ value_w,
    _Float16* __restrict__ W3T)
{
    const int tid = threadIdx.x;
    const int c = blockIdx.x;      // d-chunk of 256
    const int g = blockIdx.y;      // slot group of 8
    const int d = c * 256 + tid;

    __shared__ __align__(16) float mem_s[8 * MDIM];
    for (int i = tid; i < 8 * MDIM; i += 256)
        mem_s[i] = memory[g * 8 * MDIM + i];
    __syncthreads();

    const f32x4* ms4 = (const f32x4*)mem_s;
    const f32x4* vp = (const f32x4*)(value_w + (size_t)d * MDIM);
    float acc[8] = {};
    for (int m4 = 0; m4 < MDIM / 4; ++m4) {
        const f32x4 v = vp[m4];
        #pragma unroll
        for (int i = 0; i < 8; ++i) {
            const f32x4 mv = ms4[i * (MDIM / 4) + m4];
            acc[i] = fmaf(mv.x, v.x, acc[i]);
            acc[i] = fmaf(mv.y, v.y, acc[i]);
            acc[i] = fmaf(mv.z, v.z, acc[i]);
            acc[i] = fmaf(mv.w, v.w, acc[i]);
        }
    }
    #pragma unroll
    for (int i = 0; i < 8; ++i)
        W3T[(size_t)d * NSLOT + g * 8 + i] = (_Float16)acc[i];
}

__global__ __launch_bounds__(256) void prep_t(
    const float* __restrict__ value_w, const float* __restrict__ gate_w,
    float* __restrict__ tpart)
{
    const int b = blockIdx.x;      // d-chunk of 256
    const int tid = threadIdx.x;
    float a0 = 0.f, a1 = 0.f;
    for (int d = b * 256; d < b * 256 + 256; ++d) {
        const float gv = gate_w[DIM + d];
        a0 = fmaf(value_w[(size_t)d * MDIM + tid], gv, a0);
        a1 = fmaf(value_w[(size_t)d * MDIM + tid + 256], gv, a1);
    }
    tpart[b * 512 + tid] = a0;
    tpart[b * 512 + tid + 256] = a1;
}

__global__ __launch_bounds__(512) void prep_h(
    const float* __restrict__ memory, const float* __restrict__ tpart,
    float* __restrict__ h)
{
    __shared__ float ts[512];
    const int tid = threadIdx.x;
    float s = 0.f;
    #pragma unroll
    for (int b = 0; b < 8; ++b) s += tpart[b * 512 + tid];
    ts[tid] = s;
    __syncthreads();
    const int lane = tid & 63, w = tid >> 6;
    #pragma unroll
    for (int q = 0; q < 8; ++q) {
        const int n = w * 8 + q;
        float p = 0.f;
        for (int m = lane; m < MDIM; m += 64)
            p = fmaf(memory[(size_t)n * MDIM + m], ts[m], p);
        #pragma unroll
        for (int off = 32; off; off >>= 1) p += __shfl_xor(p, off);
        if (lane == 0) h[n] = p;
    }
}

// ============================ fused kernel =================================
// BARRIER-FREE. R8 math (validated); W2 fragments read directly from the
// fragment-packed W2F through L2 (640 KB hot set, L2-resident) instead of
// LDS staging -> zero __syncthreads in the whole kernel, VMEM pipeline never
// drains. 256 threads / 4 waves; wave = m-tile (16 rows); 512 blocks.
// attn/gate handoff is wave-local LDS (no barrier, R6-validated).
// Phase B = R8 verbatim (swapped-operand MFMA, float4 mix, 4-deep rotation).

__global__ __launch_bounds__(256) void fused_kernel(
    const float* __restrict__ x,
    const _Float16* __restrict__ W2F,
    const _Float16* __restrict__ W3T,
    const float* __restrict__ h, const float* __restrict__ gate_b,
    float* __restrict__ out)
{
    __shared__ __align__(16) _Float16 attn_s[4][16][72];   // 9 KB
    __shared__ float gate_s[4][16];

    const int tid  = threadIdx.x;
    const int lane = tid & 63;
    const int w    = tid >> 6;          // wave = m-tile 0..3
    const int arow = lane & 15;
    const int kg   = lane >> 4;
    const size_t row0 = (size_t)blockIdx.x * 64;

    f32x4 acc[5];
    {   f32x4 z = {0.f, 0.f, 0.f, 0.f};
        #pragma unroll
        for (int t = 0; t < 5; ++t) acc[t] = z; }

    const float* xrow = x + (row0 + w * 16 + arow) * DIM + kg * 8;
    const _Float16* w2l8 = W2F + lane * 8;   // lane's slot within each 512-half group

    f32x4 xA[8], xB[8];
    auto load_x = [&](f32x4* X, int chn) {
        #pragma unroll
        for (int ks = 0; ks < 4; ++ks) {
            X[ks * 2]     = *(const f32x4*)(xrow + chn * 128 + ks * 32);
            X[ks * 2 + 1] = *(const f32x4*)(xrow + chn * 128 + ks * 32 + 4);
        }
    };
    auto compute_chunk = [&](const f32x4* X, int ch) {
        #pragma unroll
        for (int ks = 0; ks < 4; ++ks) {
            const f32x4 xa = X[ks * 2];
            const f32x4 xb = X[ks * 2 + 1];
            const float xf[8] = {xa.x, xa.y, xa.z, xa.w, xb.x, xb.y, xb.z, xb.w};
            _Float16 hh[8], ll[8];
            #pragma unroll
            for (int u = 0; u < 8; ++u) {
                hh[u] = (_Float16)xf[u];
                ll[u] = (_Float16)(xf[u] - (float)hh[u]);
            }
            const half8 ah = {hh[0], hh[1], hh[2], hh[3], hh[4], hh[5], hh[6], hh[7]};
            const half8 al = {ll[0], ll[1], ll[2], ll[3], ll[4], ll[5], ll[6], ll[7]};
            #pragma unroll
            for (int t = 0; t < 5; ++t) {
                // group index (((ch*5+t)*4+ks)*2+lvl), 512 halfs per group
                const _Float16* p = w2l8 + (size_t)(((ch * 5 + t) * 4 + ks) * 2) * 512;
                const half8 bh = *(const half8*)p;
                const half8 bl = *(const half8*)(p + 512);
                acc[t] = MFMA16(ah, bh, acc[t]);
                acc[t] = MFMA16(al, bh, acc[t]);
                acc[t] = MFMA16(ah, bl, acc[t]);
            }
        }
    };

    // ---- phase A: 16 chunks, x double-buffered, NO BARRIERS ----
    load_x(xA, 0);
    for (int chp = 0; chp < 16; chp += 2) {
        load_x(xB, chp + 1);
        compute_chunk(xA, chp);
        if (chp + 2 < 16) load_x(xA, chp + 2);
        compute_chunk(xB, chp + 1);
    }

    // ---- in-register softmax + gate (R8 verbatim, wave-local LDS out) ----
    float hl[4];
    #pragma unroll
    for (int t = 0; t < 4; ++t) hl[t] = h[t * 16 + arow];
    const float gb = gate_b[0];

    #pragma unroll
    for (int j = 0; j < 4; ++j) {
        float m = fmaxf(fmaxf(acc[0][j], acc[1][j]), fmaxf(acc[2][j], acc[3][j]));
        #pragma unroll
        for (int off = 1; off < 16; off <<= 1) m = fmaxf(m, __shfl_xor(m, off));
        float p[4];
        float sum = 0.f;
        #pragma unroll
        for (int t = 0; t < 4; ++t) { p[t] = __expf((acc[t][j] - m) * TINV); sum += p[t]; }
        #pragma unroll
        for (int off = 1; off < 16; off <<= 1) sum += __shfl_xor(sum, off);
        const float inv = 1.f / sum;
        float gp = 0.f;
        #pragma unroll
        for (int t = 0; t < 4; ++t) {
            const float a = p[t] * inv;
            attn_s[w][kg * 4 + j][t * 16 + arow] = (_Float16)a;
            gp = fmaf(a, hl[t], gp);
        }
        #pragma unroll
        for (int off = 1; off < 16; off <<= 1) gp += __shfl_xor(gp, off);
        const float sg = __shfl(acc[4][j], lane & 48);   // gate col (raw, no TINV)
        if (arow == 0)
            gate_s[w][kg * 4 + j] = 1.f / (1.f + __expf(-(sg + gp + gb)));
    }

    // ---- phase B: retrieve + mix (R8 verbatim, wave-local source) ----
    const size_t rbase = row0 + w * 16;
    const half8 a0 = *(const half8*)(&attn_s[w][arow][kg * 8]);
    const half8 a1 = *(const half8*)(&attn_s[w][arow][kg * 8 + 32]);
    const float g = gate_s[w][arow];

    const size_t rowoff = (rbase + arow) * DIM + kg * 4;
    const float* xp = x + rowoff;
    float* op = out + rowoff;
    const _Float16* w3base = W3T + (size_t)arow * NSLOT + kg * 8;

    half8 qb0[4], qb1[4];
    f32x4 qx[4];
    #pragma unroll
    for (int s = 0; s < 4; ++s) {
        const _Float16* bp = w3base + (size_t)s * 16 * NSLOT;
        qb0[s] = *(const half8*)bp;
        qb1[s] = *(const half8*)(bp + 32);
        qx[s]  = *(const f32x4*)(xp + s * 16);
    }

    #pragma unroll 4
    for (int dt = 0; dt < 128; ++dt) {
        const int s = dt & 3;                       // static under unroll 4
        f32x4 r = {0.f, 0.f, 0.f, 0.f};
        r = MFMA16(qb0[s], a0, r);                  // swapped operands (validated)
        r = MFMA16(qb1[s], a1, r);
        const f32x4 xv = qx[s];
        int nt = dt + 4; if (nt > 127) nt = 127;    // clamped prefetch
        const _Float16* bp = w3base + (size_t)nt * 16 * NSLOT;
        qb0[s] = *(const half8*)bp;
        qb1[s] = *(const half8*)(bp + 32);
        qx[s]  = *(const f32x4*)(xp + (size_t)nt * 16);
        f32x4 o;
        o.x = fmaf(g, xv.x - r.x, r.x);
        o.y = fmaf(g, xv.y - r.y, r.y);
        o.z = fmaf(g, xv.z - r.z, r.z);
        o.w = fmaf(g, xv.w - r.w, r.w);
        *(f32x4*)(op + dt * 16) = o;
    }
}

// ================================ launch ===================================

extern "C" void kernel_launch(void* const* d_in, const int* in_sizes, int n_in,
                              void* d_out, int out_size, void* d_ws, size_t ws_size,
                              hipStream_t stream) {
    (void)in_sizes; (void)n_in; (void)out_size; (void)ws_size;
    const float* x       = (const float*)d_in[0];
    const float* memory  = (const float*)d_in[1];
    const float* key_w   = (const float*)d_in[2];
    const float* value_w = (const float*)d_in[3];
    const float* gate_w  = (const float*)d_in[4];
    const float* gate_b  = (const float*)d_in[5];
    float* out = (float*)d_out;

    char* wsb = (char*)d_ws;                       // needs ~1.6 MB
    _Float16* W2F = (_Float16*)(wsb + OFF_W2F);
    _Float16* W3T = (_Float16*)(wsb + OFF_W3T);
    float*    h   = (float*)(wsb + OFF_H);
    float*    tpt = (float*)(wsb + OFF_TPART);

    prep_w2 <<<dim3(8, 9), 256, 0, stream>>>(memory, key_w, gate_w, W2F);
    prep_w3t<<<dim3(8, 8), 256, 0, stream>>>(memory, value_w, W3T);
    prep_t  <<<8, 256, 0, stream>>>(value_w, gate_w, tpt);
    prep_h  <<<1, 512, 0, stream>>>(memory, tpt, h);

    fused_kernel<<<512, 256, 0, stream>>>(x, W2F, W3T, h, gate_b, out);
}

// Round 11
// 301.499 us; speedup vs baseline: 1.2917x; 1.2917x over previous
//
#include <hip/hip_runtime.h>
#include <stdint.h>

#define DIM   2048
#define NSLOT 64
#define MDIM  512
#define TINV  10.0f

typedef __attribute__((ext_vector_type(4))) float     f32x4;
typedef __attribute__((ext_vector_type(8))) _Float16  half8;

#define MFMA16(a,b,c) __builtin_amdgcn_mfma_f32_16x16x32_f16((a),(b),(c),0,0,0)

// ---------------------------------------------------------------------------
// ws layout (bytes), total ~1.59 MB (identical to round 10):
//   W2F  [16ch][5t][4ks][2lvl][64lane][8] f16  (1.31 MB, fragment-packed W2)
//   W3T  [2048][64] f16
//   h    [64] f32
//   tpart[8][512] f32
// ---------------------------------------------------------------------------
#define OFF_W2F   0
#define OFF_W3T   1310720
#define OFF_H     1572864
#define OFF_TPART 1573120

__device__ __forceinline__ size_t w2f_idx(int row, int k, int lvl) {
    const int t  = row >> 4, ar = row & 15;
    const int ch = k >> 7, ks = (k >> 5) & 3, kg = (k >> 3) & 3, e = k & 7;
    return ((size_t)((((ch * 5 + t) * 4 + ks) * 2 + lvl) * 64) + kg * 16 + ar) * 8 + e;
}

// ===================== merged prep kernel (w2 | w3t | t) ====================
// grid dim3(8, 18): y in [0,9) -> prep_w2 role (g=y); y in [9,17) -> prep_w3t
// (g=y-9); y==17 -> prep_t (b=x). Bodies verbatim from round 10.

__global__ __launch_bounds__(256) void prep_all(
    const float* __restrict__ memory, const float* __restrict__ key_w,
    const float* __restrict__ value_w, const float* __restrict__ gate_w,
    _Float16* __restrict__ W2F, _Float16* __restrict__ W3T,
    float* __restrict__ tpart)
{
    const int tid = threadIdx.x;
    const int c = blockIdx.x;
    const int role = blockIdx.y;

    if (role == 17) {                       // ---- prep_t ----
        const int b = c;
        float a0 = 0.f, a1 = 0.f;
        for (int d = b * 256; d < b * 256 + 256; ++d) {
            const float gv = gate_w[DIM + d];
            a0 = fmaf(value_w[(size_t)d * MDIM + tid], gv, a0);
            a1 = fmaf(value_w[(size_t)d * MDIM + tid + 256], gv, a1);
        }
        tpart[b * 512 + tid] = a0;
        tpart[b * 512 + tid + 256] = a1;
        return;
    }

    if (role < 9) {                         // ---- prep_w2 ----
        const int g = role;
        const int k = c * 256 + tid;
        if (g == 8) {
            float v = gate_w[k];
            _Float16 ph = (_Float16)v;
            _Float16 pl = (_Float16)(v - (float)ph);
            W2F[w2f_idx(64, k, 0)] = ph;
            W2F[w2f_idx(64, k, 1)] = pl;
            for (int r = 65; r < 80; ++r) {
                W2F[w2f_idx(r, k, 0)] = (_Float16)0.f;
                W2F[w2f_idx(r, k, 1)] = (_Float16)0.f;
            }
            return;
        }
        __shared__ __align__(16) float mem_s[8 * MDIM];
        for (int i = tid; i < 8 * MDIM; i += 256)
            mem_s[i] = memory[g * 8 * MDIM + i];
        __syncthreads();

        const f32x4* ms4 = (const f32x4*)mem_s;
        float acc[8] = {};
        for (int m4 = 0; m4 < MDIM / 4; ++m4) {
            const float kw0 = key_w[(size_t)(m4 * 4 + 0) * DIM + k];
            const float kw1 = key_w[(size_t)(m4 * 4 + 1) * DIM + k];
            const float kw2 = key_w[(size_t)(m4 * 4 + 2) * DIM + k];
            const float kw3 = key_w[(size_t)(m4 * 4 + 3) * DIM + k];
            #pragma unroll
            for (int i = 0; i < 8; ++i) {
                const f32x4 mv = ms4[i * (MDIM / 4) + m4];
                acc[i] = fmaf(mv.x, kw0, acc[i]);
                acc[i] = fmaf(mv.y, kw1, acc[i]);
                acc[i] = fmaf(mv.z, kw2, acc[i]);
                acc[i] = fmaf(mv.w, kw3, acc[i]);
            }
        }
        #pragma unroll
        for (int i = 0; i < 8; ++i) {
            float v = acc[i];
            _Float16 ph = (_Float16)v;
            _Float16 pl = (_Float16)(v - (float)ph);
            W2F[w2f_idx(g * 8 + i, k, 0)] = ph;
            W2F[w2f_idx(g * 8 + i, k, 1)] = pl;
        }
        return;
    }

    {                                       // ---- prep_w3t ----
        const int g = role - 9;
        const int d = c * 256 + tid;
        __shared__ __align__(16) float mem_s2[8 * MDIM];
        for (int i = tid; i < 8 * MDIM; i += 256)
            mem_s2[i] = memory[g * 8 * MDIM + i];
        __syncthreads();

        const f32x4* ms4 = (const f32x4*)mem_s2;
        const f32x4* vp = (const f32x4*)(value_w + (size_t)d * MDIM);
        float acc[8] = {};
        for (int m4 = 0; m4 < MDIM / 4; ++m4) {
            const f32x4 v = vp[m4];
            #pragma unroll
            for (int i = 0; i < 8; ++i) {
                const f32x4 mv = ms4[i * (MDIM / 4) + m4];
                acc[i] = fmaf(mv.x, v.x, acc[i]);
                acc[i] = fmaf(mv.y, v.y, acc[i]);
                acc[i] = fmaf(mv.z, v.z, acc[i]);
                acc[i] = fmaf(mv.w, v.w, acc[i]);
            }
        }
        #pragma unroll
        for (int i = 0; i < 8; ++i)
            W3T[(size_t)d * NSLOT + g * 8 + i] = (_Float16)acc[i];
    }
}

__global__ __launch_bounds__(512) void prep_h(
    const float* __restrict__ memory, const float* __restrict__ tpart,
    float* __restrict__ h)
{
    __shared__ float ts[512];
    const int tid = threadIdx.x;
    float s = 0.f;
    #pragma unroll
    for (int b = 0; b < 8; ++b) s += tpart[b * 512 + tid];
    ts[tid] = s;
    __syncthreads();
    const int lane = tid & 63, w = tid >> 6;
    #pragma unroll
    for (int q = 0; q < 8; ++q) {
        const int n = w * 8 + q;
        float p = 0.f;
        for (int m = lane; m < MDIM; m += 64)
            p = fmaf(memory[(size_t)n * MDIM + m], ts[m], p);
        #pragma unroll
        for (int off = 32; off; off >>= 1) p += __shfl_xor(p, off);
        if (lane == 0) h[n] = p;
    }
}

// ============================ fused kernel =================================
// Barrier-free phase A (R10's fragment-packed L2 W2F reads, validated) +
// K-split 2x waves (R9's (mt,kh) decomposition + LDS combine, validated) +
// launch_bounds(512,4) so VGPR<=128 -> 16 waves/CU.
// 512 threads / 8 waves; wave = (mt = w&3, kh = w>>2); wave kh covers chunks
// kh*8..kh*8+7 (half of K). Only TWO barriers per block (combine + attn
// visibility) vs 33 in R8/R9. Phase B = R9 verbatim ((mt,dh=kh), 64 iters,
// 4-deep rotation).

__global__ __launch_bounds__(512, 4) void fused_kernel(
    const float* __restrict__ x,
    const _Float16* __restrict__ W2F,
    const _Float16* __restrict__ W3T,
    const float* __restrict__ h, const float* __restrict__ gate_b,
    float* __restrict__ out)
{
    __shared__ __align__(16) float ppart[4 * 5 * 64 * 4];  // 20 KB partials
    __shared__ __align__(16) _Float16 attn_s[4][16][72];   // 9 KB
    __shared__ float gate_s[4][16];

    const int tid  = threadIdx.x;
    const int lane = tid & 63;
    const int w    = tid >> 6;          // wave 0..7
    const int mt   = w & 3;             // m-tile
    const int kh   = w >> 2;            // k-half
    const int arow = lane & 15;
    const int kg   = lane >> 4;
    const size_t row0 = (size_t)blockIdx.x * 64;

    f32x4 acc[5];
    {   f32x4 z = {0.f, 0.f, 0.f, 0.f};
        #pragma unroll
        for (int t = 0; t < 5; ++t) acc[t] = z; }

    const float* xrow = x + (row0 + mt * 16 + arow) * DIM + kg * 8;
    const _Float16* w2l8 = W2F + lane * 8;
    const int chbase = kh * 8;

    f32x4 xA[8], xB[8];
    auto load_x = [&](f32x4* X, int chn) {
        #pragma unroll
        for (int ks = 0; ks < 4; ++ks) {
            X[ks * 2]     = *(const f32x4*)(xrow + chn * 128 + ks * 32);
            X[ks * 2 + 1] = *(const f32x4*)(xrow + chn * 128 + ks * 32 + 4);
        }
    };
    auto compute_chunk = [&](const f32x4* X, int ch) {
        #pragma unroll
        for (int ks = 0; ks < 4; ++ks) {
            const f32x4 xa = X[ks * 2];
            const f32x4 xb = X[ks * 2 + 1];
            const float xf[8] = {xa.x, xa.y, xa.z, xa.w, xb.x, xb.y, xb.z, xb.w};
            _Float16 hh[8], ll[8];
            #pragma unroll
            for (int u = 0; u < 8; ++u) {
                hh[u] = (_Float16)xf[u];
                ll[u] = (_Float16)(xf[u] - (float)hh[u]);
            }
            const half8 ah = {hh[0], hh[1], hh[2], hh[3], hh[4], hh[5], hh[6], hh[7]};
            const half8 al = {ll[0], ll[1], ll[2], ll[3], ll[4], ll[5], ll[6], ll[7]};
            #pragma unroll
            for (int t = 0; t < 5; ++t) {
                const _Float16* p = w2l8 + (size_t)(((ch * 5 + t) * 4 + ks) * 2) * 512;
                const half8 bh = *(const half8*)p;
                const half8 bl = *(const half8*)(p + 512);
                acc[t] = MFMA16(ah, bh, acc[t]);
                acc[t] = MFMA16(al, bh, acc[t]);
                acc[t] = MFMA16(ah, bl, acc[t]);
            }
        }
    };

    // ---- phase A: 8 chunks (this wave's k-half), x double-buffered, no barriers
    load_x(xA, chbase);
    for (int cp = 0; cp < 8; cp += 2) {
        load_x(xB, chbase + cp + 1);
        compute_chunk(xA, chbase + cp);
        if (cp + 2 < 8) load_x(xA, chbase + cp + 2);
        compute_chunk(xB, chbase + cp + 1);
    }

    // ---- K-split combine (R9-validated pattern, 2 barriers total) ----
    if (kh == 1) {
        #pragma unroll
        for (int t = 0; t < 5; ++t)
            *(f32x4*)(ppart + (size_t)((mt * 5 + t) * 64 + lane) * 4) = acc[t];
    }
    __syncthreads();

    if (kh == 0) {
        #pragma unroll
        for (int t = 0; t < 5; ++t)
            acc[t] += *(const f32x4*)(ppart + (size_t)((mt * 5 + t) * 64 + lane) * 4);

        // ---- in-register softmax + gate (R9 verbatim) ----
        float hl[4];
        #pragma unroll
        for (int t = 0; t < 4; ++t) hl[t] = h[t * 16 + arow];
        const float gb = gate_b[0];

        #pragma unroll
        for (int j = 0; j < 4; ++j) {
            float m = fmaxf(fmaxf(acc[0][j], acc[1][j]), fmaxf(acc[2][j], acc[3][j]));
            #pragma unroll
            for (int off = 1; off < 16; off <<= 1) m = fmaxf(m, __shfl_xor(m, off));
            float p[4];
            float sum = 0.f;
            #pragma unroll
            for (int t = 0; t < 4; ++t) { p[t] = __expf((acc[t][j] - m) * TINV); sum += p[t]; }
            #pragma unroll
            for (int off = 1; off < 16; off <<= 1) sum += __shfl_xor(sum, off);
            const float inv = 1.f / sum;
            float gp = 0.f;
            #pragma unroll
            for (int t = 0; t < 4; ++t) {
                const float a = p[t] * inv;
                attn_s[mt][kg * 4 + j][t * 16 + arow] = (_Float16)a;
                gp = fmaf(a, hl[t], gp);
            }
            #pragma unroll
            for (int off = 1; off < 16; off <<= 1) gp += __shfl_xor(gp, off);
            const float sg = __shfl(acc[4][j], lane & 48);
            if (arow == 0)
                gate_s[mt][kg * 4 + j] = 1.f / (1.f + __expf(-(sg + gp + gb)));
        }
    }
    __syncthreads();                // attn/gate visible to all waves

    // ---- phase B: retrieve + mix (R9 verbatim: (mt, dh=kh), 4-deep) ----
    const size_t rbase = row0 + mt * 16;
    const half8 a0 = *(const half8*)(&attn_s[mt][arow][kg * 8]);
    const half8 a1 = *(const half8*)(&attn_s[mt][arow][kg * 8 + 32]);
    const float g = gate_s[mt][arow];

    const size_t rowoff = (rbase + arow) * DIM + kh * 1024 + kg * 4;
    const float* xp = x + rowoff;
    float* op = out + rowoff;
    const _Float16* w3base = W3T + (size_t)(kh * 1024 + arow) * NSLOT + kg * 8;

    half8 qb0[4], qb1[4];
    f32x4 qx[4];
    #pragma unroll
    for (int s = 0; s < 4; ++s) {
        const _Float16* bp = w3base + (size_t)s * 16 * NSLOT;
        qb0[s] = *(const half8*)bp;
        qb1[s] = *(const half8*)(bp + 32);
        qx[s]  = *(const f32x4*)(xp + s * 16);
    }

    #pragma unroll 4
    for (int dt = 0; dt < 64; ++dt) {
        const int s = dt & 3;
        f32x4 r = {0.f, 0.f, 0.f, 0.f};
        r = MFMA16(qb0[s], a0, r);
        r = MFMA16(qb1[s], a1, r);
        const f32x4 xv = qx[s];
        int nt = dt + 4; if (nt > 63) nt = 63;
        const _Float16* bp = w3base + (size_t)nt * 16 * NSLOT;
        qb0[s] = *(const half8*)bp;
        qb1[s] = *(const half8*)(bp + 32);
        qx[s]  = *(const f32x4*)(xp + (size_t)nt * 16);
        f32x4 o;
        o.x = fmaf(g, xv.x - r.x, r.x);
        o.y = fmaf(g, xv.y - r.y, r.y);
        o.z = fmaf(g, xv.z - r.z, r.z);
        o.w = fmaf(g, xv.w - r.w, r.w);
        *(f32x4*)(op + dt * 16) = o;
    }
}

// ================================ launch ===================================

extern "C" void kernel_launch(void* const* d_in, const int* in_sizes, int n_in,
                              void* d_out, int out_size, void* d_ws, size_t ws_size,
                              hipStream_t stream) {
    (void)in_sizes; (void)n_in; (void)out_size; (void)ws_size;
    const float* x       = (const float*)d_in[0];
    const float* memory  = (const float*)d_in[1];
    const float* key_w   = (const float*)d_in[2];
    const float* value_w = (const float*)d_in[3];
    const float* gate_w  = (const float*)d_in[4];
    const float* gate_b  = (const float*)d_in[5];
    float* out = (float*)d_out;

    char* wsb = (char*)d_ws;                       // needs ~1.6 MB
    _Float16* W2F = (_Float16*)(wsb + OFF_W2F);
    _Float16* W3T = (_Float16*)(wsb + OFF_W3T);
    float*    h   = (float*)(wsb + OFF_H);
    float*    tpt = (float*)(wsb + OFF_TPART);

    prep_all<<<dim3(8, 18), 256, 0, stream>>>(memory, key_w, value_w, gate_w,
                                              W2F, W3T, tpt);
    prep_h  <<<1, 512, 0, stream>>>(memory, tpt, h);

    fused_kernel<<<512, 512, 0, stream>>>(x, W2F, W3T, h, gate_b, out);
}

// Round 12
// 296.012 us; speedup vs baseline: 1.3156x; 1.0185x over previous
//
#include <hip/hip_runtime.h>
#include <stdint.h>

#define DIM   2048
#define NSLOT 64
#define MDIM  512
#define TINV  10.0f

typedef __attribute__((ext_vector_type(4))) float     f32x4;
typedef __attribute__((ext_vector_type(8))) _Float16  half8;

#define MFMA16(a,b,c) __builtin_amdgcn_mfma_f32_16x16x32_f16((a),(b),(c),0,0,0)

// ---------------------------------------------------------------------------
// ws layout (bytes), total ~1.59 MB (identical to rounds 10/11):
//   W2F  [16ch][5t][4ks][2lvl][64lane][8] f16  (fragment-packed W2, L2-resident)
//   W3T  [2048][64] f16
//   h    [64] f32
//   tpart[8][512] f32
// ---------------------------------------------------------------------------
#define OFF_W2F   0
#define OFF_W3T   1310720
#define OFF_H     1572864
#define OFF_TPART 1573120

__device__ __forceinline__ size_t w2f_idx(int row, int k, int lvl) {
    const int t  = row >> 4, ar = row & 15;
    const int ch = k >> 7, ks = (k >> 5) & 3, kg = (k >> 3) & 3, e = k & 7;
    return ((size_t)((((ch * 5 + t) * 4 + ks) * 2 + lvl) * 64) + kg * 16 + ar) * 8 + e;
}

// ===================== merged prep kernel (w2 | w3t | t) ====================
// (byte-identical to round 11, validated)

__global__ __launch_bounds__(256) void prep_all(
    const float* __restrict__ memory, const float* __restrict__ key_w,
    const float* __restrict__ value_w, const float* __restrict__ gate_w,
    _Float16* __restrict__ W2F, _Float16* __restrict__ W3T,
    float* __restrict__ tpart)
{
    const int tid = threadIdx.x;
    const int c = blockIdx.x;
    const int role = blockIdx.y;

    if (role == 17) {                       // ---- prep_t ----
        const int b = c;
        float a0 = 0.f, a1 = 0.f;
        for (int d = b * 256; d < b * 256 + 256; ++d) {
            const float gv = gate_w[DIM + d];
            a0 = fmaf(value_w[(size_t)d * MDIM + tid], gv, a0);
            a1 = fmaf(value_w[(size_t)d * MDIM + tid + 256], gv, a1);
        }
        tpart[b * 512 + tid] = a0;
        tpart[b * 512 + tid + 256] = a1;
        return;
    }

    if (role < 9) {                         // ---- prep_w2 ----
        const int g = role;
        const int k = c * 256 + tid;
        if (g == 8) {
            float v = gate_w[k];
            _Float16 ph = (_Float16)v;
            _Float16 pl = (_Float16)(v - (float)ph);
            W2F[w2f_idx(64, k, 0)] = ph;
            W2F[w2f_idx(64, k, 1)] = pl;
            for (int r = 65; r < 80; ++r) {
                W2F[w2f_idx(r, k, 0)] = (_Float16)0.f;
                W2F[w2f_idx(r, k, 1)] = (_Float16)0.f;
            }
            return;
        }
        __shared__ __align__(16) float mem_s[8 * MDIM];
        for (int i = tid; i < 8 * MDIM; i += 256)
            mem_s[i] = memory[g * 8 * MDIM + i];
        __syncthreads();

        const f32x4* ms4 = (const f32x4*)mem_s;
        float acc[8] = {};
        for (int m4 = 0; m4 < MDIM / 4; ++m4) {
            const float kw0 = key_w[(size_t)(m4 * 4 + 0) * DIM + k];
            const float kw1 = key_w[(size_t)(m4 * 4 + 1) * DIM + k];
            const float kw2 = key_w[(size_t)(m4 * 4 + 2) * DIM + k];
            const float kw3 = key_w[(size_t)(m4 * 4 + 3) * DIM + k];
            #pragma unroll
            for (int i = 0; i < 8; ++i) {
                const f32x4 mv = ms4[i * (MDIM / 4) + m4];
                acc[i] = fmaf(mv.x, kw0, acc[i]);
                acc[i] = fmaf(mv.y, kw1, acc[i]);
                acc[i] = fmaf(mv.z, kw2, acc[i]);
                acc[i] = fmaf(mv.w, kw3, acc[i]);
            }
        }
        #pragma unroll
        for (int i = 0; i < 8; ++i) {
            float v = acc[i];
            _Float16 ph = (_Float16)v;
            _Float16 pl = (_Float16)(v - (float)ph);
            W2F[w2f_idx(g * 8 + i, k, 0)] = ph;
            W2F[w2f_idx(g * 8 + i, k, 1)] = pl;
        }
        return;
    }

    {                                       // ---- prep_w3t ----
        const int g = role - 9;
        const int d = c * 256 + tid;
        __shared__ __align__(16) float mem_s2[8 * MDIM];
        for (int i = tid; i < 8 * MDIM; i += 256)
            mem_s2[i] = memory[g * 8 * MDIM + i];
        __syncthreads();

        const f32x4* ms4 = (const f32x4*)mem_s2;
        const f32x4* vp = (const f32x4*)(value_w + (size_t)d * MDIM);
        float acc[8] = {};
        for (int m4 = 0; m4 < MDIM / 4; ++m4) {
            const f32x4 v = vp[m4];
            #pragma unroll
            for (int i = 0; i < 8; ++i) {
                const f32x4 mv = ms4[i * (MDIM / 4) + m4];
                acc[i] = fmaf(mv.x, v.x, acc[i]);
                acc[i] = fmaf(mv.y, v.y, acc[i]);
                acc[i] = fmaf(mv.z, v.z, acc[i]);
                acc[i] = fmaf(mv.w, v.w, acc[i]);
            }
        }
        #pragma unroll
        for (int i = 0; i < 8; ++i)
            W3T[(size_t)d * NSLOT + g * 8 + i] = (_Float16)acc[i];
    }
}

__global__ __launch_bounds__(512) void prep_h(
    const float* __restrict__ memory, const float* __restrict__ tpart,
    float* __restrict__ h)
{
    __shared__ float ts[512];
    const int tid = threadIdx.x;
    float s = 0.f;
    #pragma unroll
    for (int b = 0; b < 8; ++b) s += tpart[b * 512 + tid];
    ts[tid] = s;
    __syncthreads();
    const int lane = tid & 63, w = tid >> 6;
    #pragma unroll
    for (int q = 0; q < 8; ++q) {
        const int n = w * 8 + q;
        float p = 0.f;
        for (int m = lane; m < MDIM; m += 64)
            p = fmaf(memory[(size_t)n * MDIM + m], ts[m], p);
        #pragma unroll
        for (int off = 32; off; off >>= 1) p += __shfl_xor(p, off);
        if (lane == 0) h[n] = p;
    }
}

// ============================ fused kernel =================================
// R8/R11 math (validated). NEW: x staged per chunk (64x128 f32 = 32 KB) into
// double-buffered LDS via global_load_lds width=16 (DMA queue carries bytes
// in flight, no VGPRs), with counted vmcnt(8) + raw s_barrier so chunk ch+2's
// DMA overlaps chunk ch+1's compute (T3/T4 pattern). Source-side XOR granule
// swizzle (granule ^= row&7) + identical XOR on the ds_read side kills the
// 16-way bank conflict of a row-major [64][128] tile (rule #21).
// 256 threads / 4 waves; wave = m-tile. W2F fragment reads from L2 unchanged.
// Softmax/gate/phase-B byte-identical to R8.

__global__ __launch_bounds__(256) void fused_kernel(
    const float* __restrict__ x,
    const _Float16* __restrict__ W2F,
    const _Float16* __restrict__ W3T,
    const float* __restrict__ h, const float* __restrict__ gate_b,
    float* __restrict__ out)
{
    __shared__ __align__(16) float xs[2][64 * 128];         // 64 KB double buffer
    __shared__ __align__(16) _Float16 attn_s[4][16][72];    // 9 KB
    __shared__ float gate_s[4][16];

    const int tid  = threadIdx.x;
    const int lane = tid & 63;
    const int w    = tid >> 6;          // wave = m-tile 0..3
    const int arow = lane & 15;
    const int kg   = lane >> 4;
    const size_t row0 = (size_t)blockIdx.x * 64;

    f32x4 acc[5];
    {   f32x4 z = {0.f, 0.f, 0.f, 0.f};
        #pragma unroll
        for (int t = 0; t < 5; ++t) acc[t] = z; }

    const _Float16* w2l8 = W2F + lane * 8;

    // ---- async DMA staging: 8 issues/thread/chunk, linear LDS dest,
    //      source pre-swizzled (granule ^= row&7) ----
    auto stage = [&](int buf, int ch) {
        #pragma unroll
        for (int i = 0; i < 8; ++i) {
            const int row = i * 8 + w * 2 + (lane >> 5);
            const int srcoff = ((lane & 31) << 4) ^ ((row & 7) << 4);  // bytes in 512B row
            const float* src = x + (size_t)(row0 + row) * DIM + ch * 128 + (srcoff >> 2);
            float* dst = &xs[buf][(i * 8 + w * 2) * 128];              // wave-uniform base
            __builtin_amdgcn_global_load_lds(
                (const __attribute__((address_space(1))) void*)src,
                (__attribute__((address_space(3))) void*)dst, 16, 0, 0);
        }
    };

    auto compute_chunk = [&](int buf, int ch) {
        const int myrow = w * 16 + arow;
        const char* xrb = (const char*)&xs[buf][myrow * 128];
        const int rsw = (myrow & 7) << 4;
        #pragma unroll
        for (int ks = 0; ks < 4; ++ks) {
            const f32x4 xa = *(const f32x4*)(xrb + ((ks * 128 + kg * 32) ^ rsw));
            const f32x4 xb = *(const f32x4*)(xrb + ((ks * 128 + kg * 32 + 16) ^ rsw));
            const float xf[8] = {xa.x, xa.y, xa.z, xa.w, xb.x, xb.y, xb.z, xb.w};
            _Float16 hh[8], ll[8];
            #pragma unroll
            for (int u = 0; u < 8; ++u) {
                hh[u] = (_Float16)xf[u];
                ll[u] = (_Float16)(xf[u] - (float)hh[u]);
            }
            const half8 ah = {hh[0], hh[1], hh[2], hh[3], hh[4], hh[5], hh[6], hh[7]};
            const half8 al = {ll[0], ll[1], ll[2], ll[3], ll[4], ll[5], ll[6], ll[7]};
            #pragma unroll
            for (int t = 0; t < 5; ++t) {
                const _Float16* p = w2l8 + (size_t)(((ch * 5 + t) * 4 + ks) * 2) * 512;
                const half8 bh = *(const half8*)p;
                const half8 bl = *(const half8*)(p + 512);
                acc[t] = MFMA16(ah, bh, acc[t]);
                acc[t] = MFMA16(al, bh, acc[t]);
                acc[t] = MFMA16(ah, bl, acc[t]);
            }
        }
    };

    // ---- phase A: 16 chunks, DMA double-buffered, counted vmcnt ----
    stage(0, 0);
    stage(1, 1);
    #pragma unroll 1
    for (int ch = 0; ch < 16; ++ch) {
        if (ch < 15) asm volatile("s_waitcnt vmcnt(8)" ::: "memory");
        else         asm volatile("s_waitcnt vmcnt(0)" ::: "memory");
        __builtin_amdgcn_s_barrier();            // all waves' chunk-ch DMA landed
        asm volatile("" ::: "memory");
        compute_chunk(ch & 1, ch);
        asm volatile("" ::: "memory");
        __builtin_amdgcn_s_barrier();            // all waves done reading buf ch&1
        asm volatile("" ::: "memory");
        if (ch + 2 < 16) stage(ch & 1, ch + 2);  // refill; stays in flight
    }

    // ---- in-register softmax + gate (R8 verbatim) ----
    float hl[4];
    #pragma unroll
    for (int t = 0; t < 4; ++t) hl[t] = h[t * 16 + arow];
    const float gb = gate_b[0];

    #pragma unroll
    for (int j = 0; j < 4; ++j) {
        float m = fmaxf(fmaxf(acc[0][j], acc[1][j]), fmaxf(acc[2][j], acc[3][j]));
        #pragma unroll
        for (int off = 1; off < 16; off <<= 1) m = fmaxf(m, __shfl_xor(m, off));
        float p[4];
        float sum = 0.f;
        #pragma unroll
        for (int t = 0; t < 4; ++t) { p[t] = __expf((acc[t][j] - m) * TINV); sum += p[t]; }
        #pragma unroll
        for (int off = 1; off < 16; off <<= 1) sum += __shfl_xor(sum, off);
        const float inv = 1.f / sum;
        float gp = 0.f;
        #pragma unroll
        for (int t = 0; t < 4; ++t) {
            const float a = p[t] * inv;
            attn_s[w][kg * 4 + j][t * 16 + arow] = (_Float16)a;
            gp = fmaf(a, hl[t], gp);
        }
        #pragma unroll
        for (int off = 1; off < 16; off <<= 1) gp += __shfl_xor(gp, off);
        const float sg = __shfl(acc[4][j], lane & 48);   // gate col (raw, no TINV)
        if (arow == 0)
            gate_s[w][kg * 4 + j] = 1.f / (1.f + __expf(-(sg + gp + gb)));
    }

    // ---- phase B: retrieve + mix (R8 verbatim, wave-local source) ----
    const size_t rbase = row0 + w * 16;
    const half8 a0 = *(const half8*)(&attn_s[w][arow][kg * 8]);
    const half8 a1 = *(const half8*)(&attn_s[w][arow][kg * 8 + 32]);
    const float g = gate_s[w][arow];

    const size_t rowoff = (rbase + arow) * DIM + kg * 4;
    const float* xp = x + rowoff;
    float* op = out + rowoff;
    const _Float16* w3base = W3T + (size_t)arow * NSLOT + kg * 8;

    half8 qb0[4], qb1[4];
    f32x4 qx[4];
    #pragma unroll
    for (int s = 0; s < 4; ++s) {
        const _Float16* bp = w3base + (size_t)s * 16 * NSLOT;
        qb0[s] = *(const half8*)bp;
        qb1[s] = *(const half8*)(bp + 32);
        qx[s]  = *(const f32x4*)(xp + s * 16);
    }

    #pragma unroll 4
    for (int dt = 0; dt < 128; ++dt) {
        const int s = dt & 3;                       // static under unroll 4
        f32x4 r = {0.f, 0.f, 0.f, 0.f};
        r = MFMA16(qb0[s], a0, r);                  // swapped operands (validated)
        r = MFMA16(qb1[s], a1, r);
        const f32x4 xv = qx[s];
        int nt = dt + 4; if (nt > 127) nt = 127;    // clamped prefetch
        const _Float16* bp = w3base + (size_t)nt * 16 * NSLOT;
        qb0[s] = *(const half8*)bp;
        qb1[s] = *(const half8*)(bp + 32);
        qx[s]  = *(const f32x4*)(xp + (size_t)nt * 16);
        f32x4 o;
        o.x = fmaf(g, xv.x - r.x, r.x);
        o.y = fmaf(g, xv.y - r.y, r.y);
        o.z = fmaf(g, xv.z - r.z, r.z);
        o.w = fmaf(g, xv.w - r.w, r.w);
        *(f32x4*)(op + dt * 16) = o;
    }
}

// ================================ launch ===================================

extern "C" void kernel_launch(void* const* d_in, const int* in_sizes, int n_in,
                              void* d_out, int out_size, void* d_ws, size_t ws_size,
                              hipStream_t stream) {
    (void)in_sizes; (void)n_in; (void)out_size; (void)ws_size;
    const float* x       = (const float*)d_in[0];
    const float* memory  = (const float*)d_in[1];
    const float* key_w   = (const float*)d_in[2];
    const float* value_w = (const float*)d_in[3];
    const float* gate_w  = (const float*)d_in[4];
    const float* gate_b  = (const float*)d_in[5];
    float* out = (float*)d_out;

    char* wsb = (char*)d_ws;                       // needs ~1.6 MB
    _Float16* W2F = (_Float16*)(wsb + OFF_W2F);
    _Float16* W3T = (_Float16*)(wsb + OFF_W3T);
    float*    h   = (float*)(wsb + OFF_H);
    float*    tpt = (float*)(wsb + OFF_TPART);

    prep_all<<<dim3(8, 18), 256, 0, stream>>>(memory, key_w, value_w, gate_w,
                                              W2F, W3T, tpt);
    prep_h  <<<1, 512, 0, stream>>>(memory, tpt, h);

    fused_kernel<<<512, 256, 0, stream>>>(x, W2F, W3T, h, gate_b, out);
}

// Round 13
// 282.290 us; speedup vs baseline: 1.3795x; 1.0486x over previous
//
#include <hip/hip_runtime.h>
#include <stdint.h>

#define DIM   2048
#define NSLOT 64
#define MDIM  512
#define TINV  10.0f

typedef __attribute__((ext_vector_type(4))) float     f32x4;
typedef __attribute__((ext_vector_type(8))) _Float16  half8;

#define MFMA16(a,b,c) __builtin_amdgcn_mfma_f32_16x16x32_f16((a),(b),(c),0,0,0)

// ---------------------------------------------------------------------------
// ws layout (bytes), total ~1.59 MB (identical to rounds 10-12):
//   W2F  [16ch][5t][4ks][2lvl][64lane][8] f16 — fragment-packed W2; each chunk
//        ch is a CONTIGUOUS 40 KB linear image (groups (t*4+ks)*2+lvl of
//        512 halfs), so global_load_lds can DMA it to LDS with no swizzle.
//   W3T  [2048][64] f16
//   h    [64] f32
//   tpart[8][512] f32
// ---------------------------------------------------------------------------
#define OFF_W2F   0
#define OFF_W3T   1310720
#define OFF_H     1572864
#define OFF_TPART 1573120

__device__ __forceinline__ size_t w2f_idx(int row, int k, int lvl) {
    const int t  = row >> 4, ar = row & 15;
    const int ch = k >> 7, ks = (k >> 5) & 3, kg = (k >> 3) & 3, e = k & 7;
    return ((size_t)((((ch * 5 + t) * 4 + ks) * 2 + lvl) * 64) + kg * 16 + ar) * 8 + e;
}

// ===================== merged prep kernel (w2 | w3t | t) ====================
// (byte-identical to rounds 11/12, validated)

__global__ __launch_bounds__(256) void prep_all(
    const float* __restrict__ memory, const float* __restrict__ key_w,
    const float* __restrict__ value_w, const float* __restrict__ gate_w,
    _Float16* __restrict__ W2F, _Float16* __restrict__ W3T,
    float* __restrict__ tpart)
{
    const int tid = threadIdx.x;
    const int c = blockIdx.x;
    const int role = blockIdx.y;

    if (role == 17) {                       // ---- prep_t ----
        const int b = c;
        float a0 = 0.f, a1 = 0.f;
        for (int d = b * 256; d < b * 256 + 256; ++d) {
            const float gv = gate_w[DIM + d];
            a0 = fmaf(value_w[(size_t)d * MDIM + tid], gv, a0);
            a1 = fmaf(value_w[(size_t)d * MDIM + tid + 256], gv, a1);
        }
        tpart[b * 512 + tid] = a0;
        tpart[b * 512 + tid + 256] = a1;
        return;
    }

    if (role < 9) {                         // ---- prep_w2 ----
        const int g = role;
        const int k = c * 256 + tid;
        if (g == 8) {
            float v = gate_w[k];
            _Float16 ph = (_Float16)v;
            _Float16 pl = (_Float16)(v - (float)ph);
            W2F[w2f_idx(64, k, 0)] = ph;
            W2F[w2f_idx(64, k, 1)] = pl;
            for (int r = 65; r < 80; ++r) {
                W2F[w2f_idx(r, k, 0)] = (_Float16)0.f;
                W2F[w2f_idx(r, k, 1)] = (_Float16)0.f;
            }
            return;
        }
        __shared__ __align__(16) float mem_s[8 * MDIM];
        for (int i = tid; i < 8 * MDIM; i += 256)
            mem_s[i] = memory[g * 8 * MDIM + i];
        __syncthreads();

        const f32x4* ms4 = (const f32x4*)mem_s;
        float acc[8] = {};
        for (int m4 = 0; m4 < MDIM / 4; ++m4) {
            const float kw0 = key_w[(size_t)(m4 * 4 + 0) * DIM + k];
            const float kw1 = key_w[(size_t)(m4 * 4 + 1) * DIM + k];
            const float kw2 = key_w[(size_t)(m4 * 4 + 2) * DIM + k];
            const float kw3 = key_w[(size_t)(m4 * 4 + 3) * DIM + k];
            #pragma unroll
            for (int i = 0; i < 8; ++i) {
                const f32x4 mv = ms4[i * (MDIM / 4) + m4];
                acc[i] = fmaf(mv.x, kw0, acc[i]);
                acc[i] = fmaf(mv.y, kw1, acc[i]);
                acc[i] = fmaf(mv.z, kw2, acc[i]);
                acc[i] = fmaf(mv.w, kw3, acc[i]);
            }
        }
        #pragma unroll
        for (int i = 0; i < 8; ++i) {
            float v = acc[i];
            _Float16 ph = (_Float16)v;
            _Float16 pl = (_Float16)(v - (float)ph);
            W2F[w2f_idx(g * 8 + i, k, 0)] = ph;
            W2F[w2f_idx(g * 8 + i, k, 1)] = pl;
        }
        return;
    }

    {                                       // ---- prep_w3t ----
        const int g = role - 9;
        const int d = c * 256 + tid;
        __shared__ __align__(16) float mem_s2[8 * MDIM];
        for (int i = tid; i < 8 * MDIM; i += 256)
            mem_s2[i] = memory[g * 8 * MDIM + i];
        __syncthreads();

        const f32x4* ms4 = (const f32x4*)mem_s2;
        const f32x4* vp = (const f32x4*)(value_w + (size_t)d * MDIM);
        float acc[8] = {};
        for (int m4 = 0; m4 < MDIM / 4; ++m4) {
            const f32x4 v = vp[m4];
            #pragma unroll
            for (int i = 0; i < 8; ++i) {
                const f32x4 mv = ms4[i * (MDIM / 4) + m4];
                acc[i] = fmaf(mv.x, v.x, acc[i]);
                acc[i] = fmaf(mv.y, v.y, acc[i]);
                acc[i] = fmaf(mv.z, v.z, acc[i]);
                acc[i] = fmaf(mv.w, v.w, acc[i]);
            }
        }
        #pragma unroll
        for (int i = 0; i < 8; ++i)
            W3T[(size_t)d * NSLOT + g * 8 + i] = (_Float16)acc[i];
    }
}

__global__ __launch_bounds__(512) void prep_h(
    const float* __restrict__ memory, const float* __restrict__ tpart,
    float* __restrict__ h)
{
    __shared__ float ts[512];
    const int tid = threadIdx.x;
    float s = 0.f;
    #pragma unroll
    for (int b = 0; b < 8; ++b) s += tpart[b * 512 + tid];
    ts[tid] = s;
    __syncthreads();
    const int lane = tid & 63, w = tid >> 6;
    #pragma unroll
    for (int q = 0; q < 8; ++q) {
        const int n = w * 8 + q;
        float p = 0.f;
        for (int m = lane; m < MDIM; m += 64)
            p = fmaf(memory[(size_t)n * MDIM + m], ts[m], p);
        #pragma unroll
        for (int off = 32; off; off >>= 1) p += __shfl_xor(p, off);
        if (lane == 0) h[n] = p;
    }
}

// ============================ fused kernel =================================
// Best-of merge, math byte-compatible with R9 (validated):
//  * W2 chunk (40 KB, fragment-packed) DMA'd to LDS via global_load_lds —
//    linear dest, linear source, conflict-free lane*16 ds_reads (no swizzle).
//  * K-split: 512 thr / 8 waves, wave = (mt=w&3, kh=w>>2); 16 waves/CU
//    (LDS 69.3 KB -> 2 blocks/CU).
//  * Raw s_barrier + single vmcnt(0) placed so the x HBM stream is issued
//    AFTER the wait and stays in flight across a full compute phase; only
//    the W2 DMA L2 round trip is exposed (~500 cyc/chunk).
//  * Softmax / combine / phase B verbatim from R9.

__global__ __launch_bounds__(512, 4) void fused_kernel(
    const float* __restrict__ x,
    const _Float16* __restrict__ W2F,
    const _Float16* __restrict__ W3T,
    const float* __restrict__ h, const float* __restrict__ gate_b,
    float* __restrict__ out)
{
    __shared__ __align__(16) _Float16 w2s[20480];           // 40 KB chunk image
    __shared__ __align__(16) float ppart[4 * 5 * 64 * 4];   // 20 KB partials
    __shared__ __align__(16) _Float16 attn_s[4][16][72];    // 9 KB
    __shared__ float gate_s[4][16];

    const int tid  = threadIdx.x;
    const int lane = tid & 63;
    const int w    = tid >> 6;          // wave 0..7
    const int mt   = w & 3;             // m-tile
    const int kh   = w >> 2;            // k-half
    const int arow = lane & 15;
    const int kg   = lane >> 4;
    const size_t row0 = (size_t)blockIdx.x * 64;

    f32x4 acc[5];
    {   f32x4 z = {0.f, 0.f, 0.f, 0.f};
        #pragma unroll
        for (int t = 0; t < 5; ++t) acc[t] = z; }

    const float* xrow = x + (row0 + mt * 16 + arow) * DIM + kg * 8;

    // ---- W2 chunk DMA: 5 issues/thread, both linear (layout is pre-packed) ----
    auto dma = [&](int ch) {
        #pragma unroll
        for (int i = 0; i < 5; ++i) {
            const char* src = (const char*)W2F + (size_t)ch * 40960 + (size_t)(i * 512 + tid) * 16;
            _Float16* dst = w2s + (size_t)(i * 512 + w * 64) * 8;   // wave-uniform base
            __builtin_amdgcn_global_load_lds(
                (const __attribute__((address_space(1))) void*)src,
                (__attribute__((address_space(3))) void*)dst, 16, 0, 0);
        }
    };

    f32x4 xA[4], xB[4];
    auto load_x = [&](f32x4* X, int chn) {
        #pragma unroll
        for (int ksi = 0; ksi < 2; ++ksi) {
            const int ks = kh * 2 + ksi;
            X[ksi * 2]     = *(const f32x4*)(xrow + chn * 128 + ks * 32);
            X[ksi * 2 + 1] = *(const f32x4*)(xrow + chn * 128 + ks * 32 + 4);
        }
    };
    auto compute_chunk = [&](const f32x4* X) {
        #pragma unroll
        for (int ksi = 0; ksi < 2; ++ksi) {
            const int ks = kh * 2 + ksi;
            const f32x4 xa = X[ksi * 2];
            const f32x4 xb = X[ksi * 2 + 1];
            const float xf[8] = {xa.x, xa.y, xa.z, xa.w, xb.x, xb.y, xb.z, xb.w};
            _Float16 hh[8], ll[8];
            #pragma unroll
            for (int u = 0; u < 8; ++u) {
                hh[u] = (_Float16)xf[u];
                ll[u] = (_Float16)(xf[u] - (float)hh[u]);
            }
            const half8 ah = {hh[0], hh[1], hh[2], hh[3], hh[4], hh[5], hh[6], hh[7]};
            const half8 al = {ll[0], ll[1], ll[2], ll[3], ll[4], ll[5], ll[6], ll[7]};
            #pragma unroll
            for (int t = 0; t < 5; ++t) {
                // group (t*4+ks)*2+lvl of 512 halfs; lane slot = lane*8
                const _Float16* p = w2s + (size_t)(t * 4 + ks) * 1024 + lane * 8;
                const half8 bh = *(const half8*)p;
                const half8 bl = *(const half8*)(p + 512);
                acc[t] = MFMA16(ah, bh, acc[t]);
                acc[t] = MFMA16(al, bh, acc[t]);
                acc[t] = MFMA16(ah, bl, acc[t]);
            }
        }
    };

    // ---- phase A: 16 chunks, single-buffer DMA, x never drained mid-flight ----
    dma(0);
    load_x(xA, 0);
    #pragma unroll 1
    for (int chp = 0; chp < 16; chp += 2) {
        asm volatile("s_waitcnt vmcnt(0)" ::: "memory");   // DMA(chp)+x(chp) landed
        __builtin_amdgcn_s_barrier();                      // LDS chunk chp visible
        load_x(xB, chp + 1);                               // x stream: in flight over compute
        asm volatile("" ::: "memory");
        compute_chunk(xA);
        asm volatile("" ::: "memory");
        __builtin_amdgcn_s_barrier();                      // all waves done reading w2s
        dma(chp + 1);

        asm volatile("s_waitcnt vmcnt(0)" ::: "memory");
        __builtin_amdgcn_s_barrier();
        if (chp + 2 < 16) load_x(xA, chp + 2);
        asm volatile("" ::: "memory");
        compute_chunk(xB);
        asm volatile("" ::: "memory");
        __builtin_amdgcn_s_barrier();
        if (chp + 2 < 16) dma(chp + 2);
    }

    // ---- K-split combine (R9 verbatim, separate ppart region) ----
    if (kh == 1) {
        #pragma unroll
        for (int t = 0; t < 5; ++t)
            *(f32x4*)(ppart + (size_t)((mt * 5 + t) * 64 + lane) * 4) = acc[t];
    }
    __syncthreads();

    if (kh == 0) {
        #pragma unroll
        for (int t = 0; t < 5; ++t)
            acc[t] += *(const f32x4*)(ppart + (size_t)((mt * 5 + t) * 64 + lane) * 4);

        // ---- in-register softmax + gate (R9 verbatim) ----
        float hl[4];
        #pragma unroll
        for (int t = 0; t < 4; ++t) hl[t] = h[t * 16 + arow];
        const float gb = gate_b[0];

        #pragma unroll
        for (int j = 0; j < 4; ++j) {
            float m = fmaxf(fmaxf(acc[0][j], acc[1][j]), fmaxf(acc[2][j], acc[3][j]));
            #pragma unroll
            for (int off = 1; off < 16; off <<= 1) m = fmaxf(m, __shfl_xor(m, off));
            float p[4];
            float sum = 0.f;
            #pragma unroll
            for (int t = 0; t < 4; ++t) { p[t] = __expf((acc[t][j] - m) * TINV); sum += p[t]; }
            #pragma unroll
            for (int off = 1; off < 16; off <<= 1) sum += __shfl_xor(sum, off);
            const float inv = 1.f / sum;
            float gp = 0.f;
            #pragma unroll
            for (int t = 0; t < 4; ++t) {
                const float a = p[t] * inv;
                attn_s[mt][kg * 4 + j][t * 16 + arow] = (_Float16)a;
                gp = fmaf(a, hl[t], gp);
            }
            #pragma unroll
            for (int off = 1; off < 16; off <<= 1) gp += __shfl_xor(gp, off);
            const float sg = __shfl(acc[4][j], lane & 48);
            if (arow == 0)
                gate_s[mt][kg * 4 + j] = 1.f / (1.f + __expf(-(sg + gp + gb)));
        }
    }
    __syncthreads();                // attn/gate visible to all waves

    // ---- phase B: retrieve + mix (R9 verbatim: (mt, dh=kh), 4-deep) ----
    const size_t rbase = row0 + mt * 16;
    const half8 a0 = *(const half8*)(&attn_s[mt][arow][kg * 8]);
    const half8 a1 = *(const half8*)(&attn_s[mt][arow][kg * 8 + 32]);
    const float g = gate_s[mt][arow];

    const size_t rowoff = (rbase + arow) * DIM + kh * 1024 + kg * 4;
    const float* xp = x + rowoff;
    float* op = out + rowoff;
    const _Float16* w3base = W3T + (size_t)(kh * 1024 + arow) * NSLOT + kg * 8;

    half8 qb0[4], qb1[4];
    f32x4 qx[4];
    #pragma unroll
    for (int s = 0; s < 4; ++s) {
        const _Float16* bp = w3base + (size_t)s * 16 * NSLOT;
        qb0[s] = *(const half8*)bp;
        qb1[s] = *(const half8*)(bp + 32);
        qx[s]  = *(const f32x4*)(xp + s * 16);
    }

    #pragma unroll 4
    for (int dt = 0; dt < 64; ++dt) {
        const int s = dt & 3;
        f32x4 r = {0.f, 0.f, 0.f, 0.f};
        r = MFMA16(qb0[s], a0, r);
        r = MFMA16(qb1[s], a1, r);
        const f32x4 xv = qx[s];
        int nt = dt + 4; if (nt > 63) nt = 63;
        const _Float16* bp = w3base + (size_t)nt * 16 * NSLOT;
        qb0[s] = *(const half8*)bp;
        qb1[s] = *(const half8*)(bp + 32);
        qx[s]  = *(const f32x4*)(xp + (size_t)nt * 16);
        f32x4 o;
        o.x = fmaf(g, xv.x - r.x, r.x);
        o.y = fmaf(g, xv.y - r.y, r.y);
        o.z = fmaf(g, xv.z - r.z, r.z);
        o.w = fmaf(g, xv.w - r.w, r.w);
        *(f32x4*)(op + dt * 16) = o;
    }
}

// ================================ launch ===================================

extern "C" void kernel_launch(void* const* d_in, const int* in_sizes, int n_in,
                              void* d_out, int out_size, void* d_ws, size_t ws_size,
                              hipStream_t stream) {
    (void)in_sizes; (void)n_in; (void)out_size; (void)ws_size;
    const float* x       = (const float*)d_in[0];
    const float* memory  = (const float*)d_in[1];
    const float* key_w   = (const float*)d_in[2];
    const float* value_w = (const float*)d_in[3];
    const float* gate_w  = (const float*)d_in[4];
    const float* gate_b  = (const float*)d_in[5];
    float* out = (float*)d_out;

    char* wsb = (char*)d_ws;                       // needs ~1.6 MB
    _Float16* W2F = (_Float16*)(wsb + OFF_W2F);
    _Float16* W3T = (_Float16*)(wsb + OFF_W3T);
    float*    h   = (float*)(wsb + OFF_H);
    float*    tpt = (float*)(wsb + OFF_TPART);

    prep_all<<<dim3(8, 18), 256, 0, stream>>>(memory, key_w, value_w, gate_w,
                                              W2F, W3T, tpt);
    prep_h  <<<1, 512, 0, stream>>>(memory, tpt, h);

    fused_kernel<<<512, 512, 0, stream>>>(x, W2F, W3T, h, gate_b, out);
}

// Round 14
// 278.333 us; speedup vs baseline: 1.3992x; 1.0142x over previous
//
#include <hip/hip_runtime.h>
#include <stdint.h>

#define DIM   2048
#define NSLOT 64
#define MDIM  512
#define TINV  10.0f

typedef __attribute__((ext_vector_type(4))) float     f32x4;
typedef __attribute__((ext_vector_type(8))) _Float16  half8;

#define MFMA16(a,b,c) __builtin_amdgcn_mfma_f32_16x16x32_f16((a),(b),(c),0,0,0)
#define AS1 __attribute__((address_space(1)))
#define AS3 __attribute__((address_space(3)))

// ---------------------------------------------------------------------------
// ws layout (bytes), total ~1.59 MB:
//   W2F  [32ch][5t][2ks][2lvl][64lane][8] f16 — fragment-packed W2, chunked by
//        K=64: each chunk ch is a CONTIGUOUS 20 KB linear image.
//        row = t*16 + (lane&15); k = ch*64 + ks*32 + (lane>>4)*8 + e
//   W3T  [2048][64] f16
//   h    [64] f32
//   tpart[8][512] f32
// ---------------------------------------------------------------------------
#define OFF_W2F   0
#define OFF_W3T   1310720
#define OFF_H     1572864
#define OFF_TPART 1573120

__device__ __forceinline__ size_t w2f_idx(int row, int k, int lvl) {
    const int t  = row >> 4, ar = row & 15;
    const int ch = k >> 6, ks = (k >> 5) & 1, kg = (k >> 3) & 3, e = k & 7;
    return ((size_t)((((ch * 5 + t) * 2 + ks) * 2 + lvl) * 64) + kg * 16 + ar) * 8 + e;
}

// ===================== merged prep kernel (w2 | w3t | t) ====================
// (bodies identical to rounds 11-13; only w2f_idx layout changed)

__global__ __launch_bounds__(256) void prep_all(
    const float* __restrict__ memory, const float* __restrict__ key_w,
    const float* __restrict__ value_w, const float* __restrict__ gate_w,
    _Float16* __restrict__ W2F, _Float16* __restrict__ W3T,
    float* __restrict__ tpart)
{
    const int tid = threadIdx.x;
    const int c = blockIdx.x;
    const int role = blockIdx.y;

    if (role == 17) {                       // ---- prep_t ----
        const int b = c;
        float a0 = 0.f, a1 = 0.f;
        for (int d = b * 256; d < b * 256 + 256; ++d) {
            const float gv = gate_w[DIM + d];
            a0 = fmaf(value_w[(size_t)d * MDIM + tid], gv, a0);
            a1 = fmaf(value_w[(size_t)d * MDIM + tid + 256], gv, a1);
        }
        tpart[b * 512 + tid] = a0;
        tpart[b * 512 + tid + 256] = a1;
        return;
    }

    if (role < 9) {                         // ---- prep_w2 ----
        const int g = role;
        const int k = c * 256 + tid;
        if (g == 8) {
            float v = gate_w[k];
            _Float16 ph = (_Float16)v;
            _Float16 pl = (_Float16)(v - (float)ph);
            W2F[w2f_idx(64, k, 0)] = ph;
            W2F[w2f_idx(64, k, 1)] = pl;
            for (int r = 65; r < 80; ++r) {
                W2F[w2f_idx(r, k, 0)] = (_Float16)0.f;
                W2F[w2f_idx(r, k, 1)] = (_Float16)0.f;
            }
            return;
        }
        __shared__ __align__(16) float mem_s[8 * MDIM];
        for (int i = tid; i < 8 * MDIM; i += 256)
            mem_s[i] = memory[g * 8 * MDIM + i];
        __syncthreads();

        const f32x4* ms4 = (const f32x4*)mem_s;
        float acc[8] = {};
        for (int m4 = 0; m4 < MDIM / 4; ++m4) {
            const float kw0 = key_w[(size_t)(m4 * 4 + 0) * DIM + k];
            const float kw1 = key_w[(size_t)(m4 * 4 + 1) * DIM + k];
            const float kw2 = key_w[(size_t)(m4 * 4 + 2) * DIM + k];
            const float kw3 = key_w[(size_t)(m4 * 4 + 3) * DIM + k];
            #pragma unroll
            for (int i = 0; i < 8; ++i) {
                const f32x4 mv = ms4[i * (MDIM / 4) + m4];
                acc[i] = fmaf(mv.x, kw0, acc[i]);
                acc[i] = fmaf(mv.y, kw1, acc[i]);
                acc[i] = fmaf(mv.z, kw2, acc[i]);
                acc[i] = fmaf(mv.w, kw3, acc[i]);
            }
        }
        #pragma unroll
        for (int i = 0; i < 8; ++i) {
            float v = acc[i];
            _Float16 ph = (_Float16)v;
            _Float16 pl = (_Float16)(v - (float)ph);
            W2F[w2f_idx(g * 8 + i, k, 0)] = ph;
            W2F[w2f_idx(g * 8 + i, k, 1)] = pl;
        }
        return;
    }

    {                                       // ---- prep_w3t ----
        const int g = role - 9;
        const int d = c * 256 + tid;
        __shared__ __align__(16) float mem_s2[8 * MDIM];
        for (int i = tid; i < 8 * MDIM; i += 256)
            mem_s2[i] = memory[g * 8 * MDIM + i];
        __syncthreads();

        const f32x4* ms4 = (const f32x4*)mem_s2;
        const f32x4* vp = (const f32x4*)(value_w + (size_t)d * MDIM);
        float acc[8] = {};
        for (int m4 = 0; m4 < MDIM / 4; ++m4) {
            const f32x4 v = vp[m4];
            #pragma unroll
            for (int i = 0; i < 8; ++i) {
                const f32x4 mv = ms4[i * (MDIM / 4) + m4];
                acc[i] = fmaf(mv.x, v.x, acc[i]);
                acc[i] = fmaf(mv.y, v.y, acc[i]);
                acc[i] = fmaf(mv.z, v.z, acc[i]);
                acc[i] = fmaf(mv.w, v.w, acc[i]);
            }
        }
        #pragma unroll
        for (int i = 0; i < 8; ++i)
            W3T[(size_t)d * NSLOT + g * 8 + i] = (_Float16)acc[i];
    }
}

__global__ __launch_bounds__(512) void prep_h(
    const float* __restrict__ memory, const float* __restrict__ tpart,
    float* __restrict__ h)
{
    __shared__ float ts[512];
    const int tid = threadIdx.x;
    float s = 0.f;
    #pragma unroll
    for (int b = 0; b < 8; ++b) s += tpart[b * 512 + tid];
    ts[tid] = s;
    __syncthreads();
    const int lane = tid & 63, w = tid >> 6;
    #pragma unroll
    for (int q = 0; q < 8; ++q) {
        const int n = w * 8 + q;
        float p = 0.f;
        for (int m = lane; m < MDIM; m += 64)
            p = fmaf(memory[(size_t)n * MDIM + m], ts[m], p);
        #pragma unroll
        for (int off = 32; off; off >>= 1) p += __shfl_xor(p, off);
        if (lane == 0) h[n] = p;
    }
}

// ============================ fused kernel =================================
// R13 math (validated) with the T3/T4 pipeline completed:
//  * W2 chunk images (20 KB, K=64) DOUBLE-BUFFERED in LDS via global_load_lds.
//  * Counted vmcnt(4) in steady state — never 0 until the final chunk — so
//    the HBM x stream (issued 2 chunks ahead) is never drained mid-flight.
//  * K-split 8 waves (mt=w&3, kh=w>>2); LDS 69.7 KB -> 2 blocks/CU.
//  * Softmax / combine / phase B verbatim from R13.

__global__ __launch_bounds__(512, 4) void fused_kernel(
    const float* __restrict__ x,
    const _Float16* __restrict__ W2F,
    const _Float16* __restrict__ W3T,
    const float* __restrict__ h, const float* __restrict__ gate_b,
    float* __restrict__ out)
{
    __shared__ __align__(16) _Float16 w2s[2][10240];        // 2 x 20 KB chunk images
    __shared__ __align__(16) float ppart[4 * 5 * 64 * 4];   // 20 KB partials
    __shared__ __align__(16) _Float16 attn_s[4][16][72];    // 9 KB
    __shared__ float gate_s[4][16];

    const int tid  = threadIdx.x;
    const int lane = tid & 63;
    const int w    = tid >> 6;          // wave 0..7
    const int mt   = w & 3;             // m-tile
    const int kh   = w >> 2;            // k-half (kstep within chunk)
    const int arow = lane & 15;
    const int kg   = lane >> 4;
    const size_t row0 = (size_t)blockIdx.x * 64;

    f32x4 acc[5];
    {   f32x4 z = {0.f, 0.f, 0.f, 0.f};
        #pragma unroll
        for (int t = 0; t < 5; ++t) acc[t] = z; }

    const float* xrow = x + (row0 + mt * 16 + arow) * DIM + kg * 8;

    // ---- W2 chunk DMA: 20 KB = 1280 granules; 2/thread + 1 extra for waves 0-3
    auto dma = [&](int ch, int buf) {
        const char* base = (const char*)W2F + (size_t)ch * 20480;
        _Float16* db = &w2s[buf][0];
        __builtin_amdgcn_global_load_lds(
            (const AS1 void*)(base + (size_t)tid * 16),
            (AS3 void*)(db + (size_t)(w * 64) * 8), 16, 0, 0);
        __builtin_amdgcn_global_load_lds(
            (const AS1 void*)(base + (size_t)(512 + tid) * 16),
            (AS3 void*)(db + (size_t)(512 + w * 64) * 8), 16, 0, 0);
        if (w < 4)
            __builtin_amdgcn_global_load_lds(
                (const AS1 void*)(base + (size_t)(1024 + tid) * 16),
                (AS3 void*)(db + (size_t)(1024 + w * 64) * 8), 16, 0, 0);
    };

    // ---- x loads: 2 dwordx4 per chunk (this wave's kstep kh) ----
    f32x4 xA[2], xB[2];
    auto load_x = [&](f32x4* X, int ch) {
        X[0] = *(const f32x4*)(xrow + ch * 64 + kh * 32);
        X[1] = *(const f32x4*)(xrow + ch * 64 + kh * 32 + 4);
    };
    auto compute_chunk = [&](const f32x4* X, int buf) {
        const f32x4 xa = X[0];
        const f32x4 xb = X[1];
        const float xf[8] = {xa.x, xa.y, xa.z, xa.w, xb.x, xb.y, xb.z, xb.w};
        _Float16 hh[8], ll[8];
        #pragma unroll
        for (int u = 0; u < 8; ++u) {
            hh[u] = (_Float16)xf[u];
            ll[u] = (_Float16)(xf[u] - (float)hh[u]);
        }
        const half8 ah = {hh[0], hh[1], hh[2], hh[3], hh[4], hh[5], hh[6], hh[7]};
        const half8 al = {ll[0], ll[1], ll[2], ll[3], ll[4], ll[5], ll[6], ll[7]};
        #pragma unroll
        for (int t = 0; t < 5; ++t) {
            // local group (t*2+kh)*2+lvl of 512 halfs; lane slot = lane*8
            const _Float16* p = &w2s[buf][0] + (size_t)((t * 2 + kh) * 2) * 512 + lane * 8;
            const half8 bh = *(const half8*)p;
            const half8 bl = *(const half8*)(p + 512);
            acc[t] = MFMA16(ah, bh, acc[t]);
            acc[t] = MFMA16(al, bh, acc[t]);
            acc[t] = MFMA16(ah, bl, acc[t]);
        }
    };

    // ---- phase A: 32 chunks, dbuf DMA, counted vmcnt (never 0 mid-loop) ----
    dma(0, 0);
    load_x(xA, 0);
    dma(1, 1);
    load_x(xB, 1);
    #pragma unroll 2
    for (int ch = 0; ch < 32; ++ch) {
        if (ch < 31) asm volatile("s_waitcnt vmcnt(4)" ::: "memory");
        else         asm volatile("s_waitcnt vmcnt(0)" ::: "memory");
        __builtin_amdgcn_s_barrier();            // chunk ch image + x(ch) ready
        asm volatile("" ::: "memory");
        compute_chunk((ch & 1) ? xB : xA, ch & 1);
        asm volatile("" ::: "memory");
        __builtin_amdgcn_s_barrier();            // all waves done reading buf
        if (ch + 2 < 32) {
            dma(ch + 2, ch & 1);                 // refill just-freed buffer
            load_x((ch & 1) ? xB : xA, ch + 2);  // x 2 chunks ahead, stays in flight
        }
    }

    // ---- K-split combine (R13 verbatim) ----
    if (kh == 1) {
        #pragma unroll
        for (int t = 0; t < 5; ++t)
            *(f32x4*)(ppart + (size_t)((mt * 5 + t) * 64 + lane) * 4) = acc[t];
    }
    __syncthreads();

    if (kh == 0) {
        #pragma unroll
        for (int t = 0; t < 5; ++t)
            acc[t] += *(const f32x4*)(ppart + (size_t)((mt * 5 + t) * 64 + lane) * 4);

        // ---- in-register softmax + gate (R13 verbatim) ----
        float hl[4];
        #pragma unroll
        for (int t = 0; t < 4; ++t) hl[t] = h[t * 16 + arow];
        const float gb = gate_b[0];

        #pragma unroll
        for (int j = 0; j < 4; ++j) {
            float m = fmaxf(fmaxf(acc[0][j], acc[1][j]), fmaxf(acc[2][j], acc[3][j]));
            #pragma unroll
            for (int off = 1; off < 16; off <<= 1) m = fmaxf(m, __shfl_xor(m, off));
            float p[4];
            float sum = 0.f;
            #pragma unroll
            for (int t = 0; t < 4; ++t) { p[t] = __expf((acc[t][j] - m) * TINV); sum += p[t]; }
            #pragma unroll
            for (int off = 1; off < 16; off <<= 1) sum += __shfl_xor(sum, off);
            const float inv = 1.f / sum;
            float gp = 0.f;
            #pragma unroll
            for (int t = 0; t < 4; ++t) {
                const float a = p[t] * inv;
                attn_s[mt][kg * 4 + j][t * 16 + arow] = (_Float16)a;
                gp = fmaf(a, hl[t], gp);
            }
            #pragma unroll
            for (int off = 1; off < 16; off <<= 1) gp += __shfl_xor(gp, off);
            const float sg = __shfl(acc[4][j], lane & 48);
            if (arow == 0)
                gate_s[mt][kg * 4 + j] = 1.f / (1.f + __expf(-(sg + gp + gb)));
        }
    }
    __syncthreads();                // attn/gate visible to all waves

    // ---- phase B: retrieve + mix (R13 verbatim: (mt, dh=kh), 4-deep) ----
    const size_t rbase = row0 + mt * 16;
    const half8 a0 = *(const half8*)(&attn_s[mt][arow][kg * 8]);
    const half8 a1 = *(const half8*)(&attn_s[mt][arow][kg * 8 + 32]);
    const float g = gate_s[mt][arow];

    const size_t rowoff = (rbase + arow) * DIM + kh * 1024 + kg * 4;
    const float* xp = x + rowoff;
    float* op = out + rowoff;
    const _Float16* w3base = W3T + (size_t)(kh * 1024 + arow) * NSLOT + kg * 8;

    half8 qb0[4], qb1[4];
    f32x4 qx[4];
    #pragma unroll
    for (int s = 0; s < 4; ++s) {
        const _Float16* bp = w3base + (size_t)s * 16 * NSLOT;
        qb0[s] = *(const half8*)bp;
        qb1[s] = *(const half8*)(bp + 32);
        qx[s]  = *(const f32x4*)(xp + s * 16);
    }

    #pragma unroll 4
    for (int dt = 0; dt < 64; ++dt) {
        const int s = dt & 3;
        f32x4 r = {0.f, 0.f, 0.f, 0.f};
        r = MFMA16(qb0[s], a0, r);
        r = MFMA16(qb1[s], a1, r);
        const f32x4 xv = qx[s];
        int nt = dt + 4; if (nt > 63) nt = 63;
        const _Float16* bp = w3base + (size_t)nt * 16 * NSLOT;
        qb0[s] = *(const half8*)bp;
        qb1[s] = *(const half8*)(bp + 32);
        qx[s]  = *(const f32x4*)(xp + (size_t)nt * 16);
        f32x4 o;
        o.x = fmaf(g, xv.x - r.x, r.x);
        o.y = fmaf(g, xv.y - r.y, r.y);
        o.z = fmaf(g, xv.z - r.z, r.z);
        o.w = fmaf(g, xv.w - r.w, r.w);
        *(f32x4*)(op + dt * 16) = o;
    }
}

// ================================ launch ===================================

extern "C" void kernel_launch(void* const* d_in, const int* in_sizes, int n_in,
                              void* d_out, int out_size, void* d_ws, size_t ws_size,
                              hipStream_t stream) {
    (void)in_sizes; (void)n_in; (void)out_size; (void)ws_size;
    const float* x       = (const float*)d_in[0];
    const float* memory  = (const float*)d_in[1];
    const float* key_w   = (const float*)d_in[2];
    const float* value_w = (const float*)d_in[3];
    const float* gate_w  = (const float*)d_in[4];
    const float* gate_b  = (const float*)d_in[5];
    float* out = (float*)d_out;

    char* wsb = (char*)d_ws;                       // needs ~1.6 MB
    _Float16* W2F = (_Float16*)(wsb + OFF_W2F);
    _Float16* W3T = (_Float16*)(wsb + OFF_W3T);
    float*    h   = (float*)(wsb + OFF_H);
    float*    tpt = (float*)(wsb + OFF_TPART);

    prep_all<<<dim3(8, 18), 256, 0, stream>>>(memory, key_w, value_w, gate_w,
                                              W2F, W3T, tpt);
    prep_h  <<<1, 512, 0, stream>>>(memory, tpt, h);

    fused_kernel<<<512, 512, 0, stream>>>(x, W2F, W3T, h, gate_b, out);
}

// Round 15
// 266.958 us; speedup vs baseline: 1.4588x; 1.0426x over previous
//
#include <hip/hip_runtime.h>
#include <stdint.h>

#define DIM   2048
#define NSLOT 64
#define MDIM  512
#define TINV  10.0f

typedef __attribute__((ext_vector_type(4))) float     f32x4;
typedef __attribute__((ext_vector_type(8))) _Float16  half8;

#define MFMA16(a,b,c) __builtin_amdgcn_mfma_f32_16x16x32_f16((a),(b),(c),0,0,0)
#define AS1 __attribute__((address_space(1)))
#define AS3 __attribute__((address_space(3)))

// ---------------------------------------------------------------------------
// ws layout (bytes):
//   W2F  [32ch] x 24576 B — fragment-packed W2, K=64 chunks, PADDED to 24 KB
//        (valid 20 KB: groups (t*2+ks)*2+lvl of 512 halfs; pad never read;
//        padding makes DMA issue count wave-uniform: 1536 granules = 3/thread)
//   W3T  [2048][64] f16
//   h    [64] f32
//   tpart[8][512] f32
// ---------------------------------------------------------------------------
#define OFF_W2F   0
#define OFF_W3T   1310720
#define OFF_H     1572864
#define OFF_TPART 1573120

__device__ __forceinline__ size_t w2f_idx(int row, int k, int lvl) {
    const int t  = row >> 4, ar = row & 15;
    const int ch = k >> 6, ks = (k >> 5) & 1, kg = (k >> 3) & 3, e = k & 7;
    return (size_t)ch * 12288 +
           ((size_t)(((t * 2 + ks) * 2 + lvl) * 64) + kg * 16 + ar) * 8 + e;
}

// ===================== merged prep kernel (w2 | w3t | t) ====================
// (bodies identical to rounds 11-14; only w2f_idx chunk stride changed)

__global__ __launch_bounds__(256) void prep_all(
    const float* __restrict__ memory, const float* __restrict__ key_w,
    const float* __restrict__ value_w, const float* __restrict__ gate_w,
    _Float16* __restrict__ W2F, _Float16* __restrict__ W3T,
    float* __restrict__ tpart)
{
    const int tid = threadIdx.x;
    const int c = blockIdx.x;
    const int role = blockIdx.y;

    if (role == 17) {                       // ---- prep_t ----
        const int b = c;
        float a0 = 0.f, a1 = 0.f;
        for (int d = b * 256; d < b * 256 + 256; ++d) {
            const float gv = gate_w[DIM + d];
            a0 = fmaf(value_w[(size_t)d * MDIM + tid], gv, a0);
            a1 = fmaf(value_w[(size_t)d * MDIM + tid + 256], gv, a1);
        }
        tpart[b * 512 + tid] = a0;
        tpart[b * 512 + tid + 256] = a1;
        return;
    }

    if (role < 9) {                         // ---- prep_w2 ----
        const int g = role;
        const int k = c * 256 + tid;
        if (g == 8) {
            float v = gate_w[k];
            _Float16 ph = (_Float16)v;
            _Float16 pl = (_Float16)(v - (float)ph);
            W2F[w2f_idx(64, k, 0)] = ph;
            W2F[w2f_idx(64, k, 1)] = pl;
            for (int r = 65; r < 80; ++r) {
                W2F[w2f_idx(r, k, 0)] = (_Float16)0.f;
                W2F[w2f_idx(r, k, 1)] = (_Float16)0.f;
            }
            return;
        }
        __shared__ __align__(16) float mem_s[8 * MDIM];
        for (int i = tid; i < 8 * MDIM; i += 256)
            mem_s[i] = memory[g * 8 * MDIM + i];
        __syncthreads();

        const f32x4* ms4 = (const f32x4*)mem_s;
        float acc[8] = {};
        for (int m4 = 0; m4 < MDIM / 4; ++m4) {
            const float kw0 = key_w[(size_t)(m4 * 4 + 0) * DIM + k];
            const float kw1 = key_w[(size_t)(m4 * 4 + 1) * DIM + k];
            const float kw2 = key_w[(size_t)(m4 * 4 + 2) * DIM + k];
            const float kw3 = key_w[(size_t)(m4 * 4 + 3) * DIM + k];
            #pragma unroll
            for (int i = 0; i < 8; ++i) {
                const f32x4 mv = ms4[i * (MDIM / 4) + m4];
                acc[i] = fmaf(mv.x, kw0, acc[i]);
                acc[i] = fmaf(mv.y, kw1, acc[i]);
                acc[i] = fmaf(mv.z, kw2, acc[i]);
                acc[i] = fmaf(mv.w, kw3, acc[i]);
            }
        }
        #pragma unroll
        for (int i = 0; i < 8; ++i) {
            float v = acc[i];
            _Float16 ph = (_Float16)v;
            _Float16 pl = (_Float16)(v - (float)ph);
            W2F[w2f_idx(g * 8 + i, k, 0)] = ph;
            W2F[w2f_idx(g * 8 + i, k, 1)] = pl;
        }
        return;
    }

    {                                       // ---- prep_w3t ----
        const int g = role - 9;
        const int d = c * 256 + tid;
        __shared__ __align__(16) float mem_s2[8 * MDIM];
        for (int i = tid; i < 8 * MDIM; i += 256)
            mem_s2[i] = memory[g * 8 * MDIM + i];
        __syncthreads();

        const f32x4* ms4 = (const f32x4*)mem_s2;
        const f32x4* vp = (const f32x4*)(value_w + (size_t)d * MDIM);
        float acc[8] = {};
        for (int m4 = 0; m4 < MDIM / 4; ++m4) {
            const f32x4 v = vp[m4];
            #pragma unroll
            for (int i = 0; i < 8; ++i) {
                const f32x4 mv = ms4[i * (MDIM / 4) + m4];
                acc[i] = fmaf(mv.x, v.x, acc[i]);
                acc[i] = fmaf(mv.y, v.y, acc[i]);
                acc[i] = fmaf(mv.z, v.z, acc[i]);
                acc[i] = fmaf(mv.w, v.w, acc[i]);
            }
        }
        #pragma unroll
        for (int i = 0; i < 8; ++i)
            W3T[(size_t)d * NSLOT + g * 8 + i] = (_Float16)acc[i];
    }
}

__global__ __launch_bounds__(512) void prep_h(
    const float* __restrict__ memory, const float* __restrict__ tpart,
    float* __restrict__ h)
{
    __shared__ float ts[512];
    const int tid = threadIdx.x;
    float s = 0.f;
    #pragma unroll
    for (int b = 0; b < 8; ++b) s += tpart[b * 512 + tid];
    ts[tid] = s;
    __syncthreads();
    const int lane = tid & 63, w = tid >> 6;
    #pragma unroll
    for (int q = 0; q < 8; ++q) {
        const int n = w * 8 + q;
        float p = 0.f;
        for (int m = lane; m < MDIM; m += 64)
            p = fmaf(memory[(size_t)n * MDIM + m], ts[m], p);
        #pragma unroll
        for (int off = 32; off; off >>= 1) p += __shfl_xor(p, off);
        if (lane == 0) h[n] = p;
    }
}

// ============================ fused kernel =================================
// R14 math (validated). Phase A rebuilt around DEEP DMA rings so in-flight
// bytes no longer depend on VGPRs:
//  * x: 4-buffer LDS ring (4 x 16 KB, K=64 chunks), DMA'd 4 chunks ahead
//    (~2400 cyc lead >> 900 cyc HBM latency). Source-granule XOR swizzle
//    gq^(row&7) + same XOR on the read side (rule #21) -> 2 lanes/bank (free).
//  * W2: 2-buffer ring of padded 24 KB fragment images (linear both sides).
//  * Uniform 5 DMA issues/wave/chunk -> counted vmcnt(7) certifies chunk ch
//    while keeping later chunks in flight; raw s_barrier (no drain).
//  * 1 block/CU (144.6 KB LDS), 8 waves. Combine/softmax/phase B = R14.

__global__ __launch_bounds__(512) void fused_kernel(
    const float* __restrict__ x,
    const _Float16* __restrict__ W2F,
    const _Float16* __restrict__ W3T,
    const float* __restrict__ h, const float* __restrict__ gate_b,
    float* __restrict__ out)
{
    __shared__ __align__(16) _Float16 w2s[2][12288];        // 48 KB (incl pad)
    __shared__ __align__(16) float    xs[4][4096];          // 64 KB x ring
    __shared__ __align__(16) float ppart[4 * 5 * 64 * 4];   // 20 KB partials
    __shared__ __align__(16) _Float16 attn_s[4][16][72];    // 9 KB
    __shared__ float gate_s[4][16];

    const int tid  = threadIdx.x;
    const int lane = tid & 63;
    const int w    = tid >> 6;          // wave 0..7
    const int mt   = w & 3;             // m-tile
    const int kh   = w >> 2;            // k-half (kstep within chunk)
    const int arow = lane & 15;
    const int kg   = lane >> 4;
    const size_t row0 = (size_t)blockIdx.x * 64;

    f32x4 acc[5];
    {   f32x4 z = {0.f, 0.f, 0.f, 0.f};
        #pragma unroll
        for (int t = 0; t < 5; ++t) acc[t] = z; }

    // ---- DMA: W2 chunk image (1536 granules, 3/thread, linear both sides) ----
    auto dmaW2 = [&](int ch, int buf) {
        const char* base = (const char*)W2F + (size_t)ch * 24576;
        char* db = (char*)&w2s[buf][0];
        #pragma unroll
        for (int i = 0; i < 3; ++i)
            __builtin_amdgcn_global_load_lds(
                (const AS1 void*)(base + (size_t)(i * 512 + tid) * 16),
                (AS3 void*)(db + (size_t)(i * 512 + w * 64) * 16), 16, 0, 0);
    };
    // ---- DMA: x chunk [64 rows][64 k] (1024 granules, 2/thread),
    //      linear dest, XOR-swizzled source granule ----
    auto dmaX = [&](int ch, int buf) {
        char* db = (char*)&xs[buf][0];
        #pragma unroll
        for (int i = 0; i < 2; ++i) {
            const int gid = i * 512 + tid;
            const int row = gid >> 4, gq = gid & 15;
            const char* src = (const char*)(x + (size_t)(row0 + row) * DIM + ch * 64)
                              + ((gq ^ (row & 7)) << 4);
            __builtin_amdgcn_global_load_lds(
                (const AS1 void*)src,
                (AS3 void*)(db + (size_t)(i * 512 + w * 64) * 16), 16, 0, 0);
        }
    };

    auto compute_chunk = [&](int xbuf, int wbuf) {
        const int row = mt * 16 + arow;
        const char* xrb = (const char*)&xs[xbuf][0] + row * 256;
        const int g0 = kh * 8 + kg * 2;
        const f32x4 xa = *(const f32x4*)(xrb + ((g0 ^ (arow & 7)) << 4));
        const f32x4 xb = *(const f32x4*)(xrb + (((g0 + 1) ^ (arow & 7)) << 4));
        const float xf[8] = {xa.x, xa.y, xa.z, xa.w, xb.x, xb.y, xb.z, xb.w};
        _Float16 hh[8], ll[8];
        #pragma unroll
        for (int u = 0; u < 8; ++u) {
            hh[u] = (_Float16)xf[u];
            ll[u] = (_Float16)(xf[u] - (float)hh[u]);
        }
        const half8 ah = {hh[0], hh[1], hh[2], hh[3], hh[4], hh[5], hh[6], hh[7]};
        const half8 al = {ll[0], ll[1], ll[2], ll[3], ll[4], ll[5], ll[6], ll[7]};
        #pragma unroll
        for (int t = 0; t < 5; ++t) {
            const _Float16* p = &w2s[wbuf][0] + (size_t)((t * 2 + kh) * 2) * 512 + lane * 8;
            const half8 bh = *(const half8*)p;
            const half8 bl = *(const half8*)(p + 512);
            acc[t] = MFMA16(ah, bh, acc[t]);
            acc[t] = MFMA16(al, bh, acc[t]);
            acc[t] = MFMA16(ah, bl, acc[t]);
        }
    };

    // ---- phase A: 32 chunks; x 4-deep, W2 2-deep, counted vmcnt(7) ----
    dmaW2(0, 0); dmaX(0, 0);
    dmaW2(1, 1); dmaX(1, 1);
    dmaX(2, 2);  dmaX(3, 3);
    #pragma unroll 4
    for (int ch = 0; ch < 32; ++ch) {
        if (ch < 28) asm volatile("s_waitcnt vmcnt(7)" ::: "memory");
        else         asm volatile("s_waitcnt vmcnt(0)" ::: "memory");
        __builtin_amdgcn_s_barrier();            // chunk ch fully in LDS (all waves)
        compute_chunk(ch & 3, ch & 1);
        __builtin_amdgcn_s_barrier();            // all waves done reading bufs
        if (ch + 2 < 32) dmaW2(ch + 2, ch & 1);  // refill just-freed W2 buf
        if (ch + 4 < 32) dmaX(ch + 4, ch & 3);   // refill just-freed x buf
    }

    // ---- K-split combine (R14 verbatim) ----
    if (kh == 1) {
        #pragma unroll
        for (int t = 0; t < 5; ++t)
            *(f32x4*)(ppart + (size_t)((mt * 5 + t) * 64 + lane) * 4) = acc[t];
    }
    __syncthreads();

    if (kh == 0) {
        #pragma unroll
        for (int t = 0; t < 5; ++t)
            acc[t] += *(const f32x4*)(ppart + (size_t)((mt * 5 + t) * 64 + lane) * 4);

        // ---- in-register softmax + gate (R14 verbatim) ----
        float hl[4];
        #pragma unroll
        for (int t = 0; t < 4; ++t) hl[t] = h[t * 16 + arow];
        const float gb = gate_b[0];

        #pragma unroll
        for (int j = 0; j < 4; ++j) {
            float m = fmaxf(fmaxf(acc[0][j], acc[1][j]), fmaxf(acc[2][j], acc[3][j]));
            #pragma unroll
            for (int off = 1; off < 16; off <<= 1) m = fmaxf(m, __shfl_xor(m, off));
            float p[4];
            float sum = 0.f;
            #pragma unroll
            for (int t = 0; t < 4; ++t) { p[t] = __expf((acc[t][j] - m) * TINV); sum += p[t]; }
            #pragma unroll
            for (int off = 1; off < 16; off <<= 1) sum += __shfl_xor(sum, off);
            const float inv = 1.f / sum;
            float gp = 0.f;
            #pragma unroll
            for (int t = 0; t < 4; ++t) {
                const float a = p[t] * inv;
                attn_s[mt][kg * 4 + j][t * 16 + arow] = (_Float16)a;
                gp = fmaf(a, hl[t], gp);
            }
            #pragma unroll
            for (int off = 1; off < 16; off <<= 1) gp += __shfl_xor(gp, off);
            const float sg = __shfl(acc[4][j], lane & 48);
            if (arow == 0)
                gate_s[mt][kg * 4 + j] = 1.f / (1.f + __expf(-(sg + gp + gb)));
        }
    }
    __syncthreads();                // attn/gate visible to all waves

    // ---- phase B: retrieve + mix (R14 verbatim: (mt, dh=kh), 4-deep) ----
    const size_t rbase = row0 + mt * 16;
    const half8 a0 = *(const half8*)(&attn_s[mt][arow][kg * 8]);
    const half8 a1 = *(const half8*)(&attn_s[mt][arow][kg * 8 + 32]);
    const float g = gate_s[mt][arow];

    const size_t rowoff = (rbase + arow) * DIM + kh * 1024 + kg * 4;
    const float* xp = x + rowoff;
    float* op = out + rowoff;
    const _Float16* w3base = W3T + (size_t)(kh * 1024 + arow) * NSLOT + kg * 8;

    half8 qb0[4], qb1[4];
    f32x4 qx[4];
    #pragma unroll
    for (int s = 0; s < 4; ++s) {
        const _Float16* bp = w3base + (size_t)s * 16 * NSLOT;
        qb0[s] = *(const half8*)bp;
        qb1[s] = *(const half8*)(bp + 32);
        qx[s]  = *(const f32x4*)(xp + s * 16);
    }

    #pragma unroll 4
    for (int dt = 0; dt < 64; ++dt) {
        const int s = dt & 3;
        f32x4 r = {0.f, 0.f, 0.f, 0.f};
        r = MFMA16(qb0[s], a0, r);
        r = MFMA16(qb1[s], a1, r);
        const f32x4 xv = qx[s];
        int nt = dt + 4; if (nt > 63) nt = 63;
        const _Float16* bp = w3base + (size_t)nt * 16 * NSLOT;
        qb0[s] = *(const half8*)bp;
        qb1[s] = *(const half8*)(bp + 32);
        qx[s]  = *(const f32x4*)(xp + (size_t)nt * 16);
        f32x4 o;
        o.x = fmaf(g, xv.x - r.x, r.x);
        o.y = fmaf(g, xv.y - r.y, r.y);
        o.z = fmaf(g, xv.z - r.z, r.z);
        o.w = fmaf(g, xv.w - r.w, r.w);
        *(f32x4*)(op + dt * 16) = o;
    }
}

// ================================ launch ===================================

extern "C" void kernel_launch(void* const* d_in, const int* in_sizes, int n_in,
                              void* d_out, int out_size, void* d_ws, size_t ws_size,
                              hipStream_t stream) {
    (void)in_sizes; (void)n_in; (void)out_size; (void)ws_size;
    const float* x       = (const float*)d_in[0];
    const float* memory  = (const float*)d_in[1];
    const float* key_w   = (const float*)d_in[2];
    const float* value_w = (const float*)d_in[3];
    const float* gate_w  = (const float*)d_in[4];
    const float* gate_b  = (const float*)d_in[5];
    float* out = (float*)d_out;

    char* wsb = (char*)d_ws;                       // needs ~1.6 MB
    _Float16* W2F = (_Float16*)(wsb + OFF_W2F);
    _Float16* W3T = (_Float16*)(wsb + OFF_W3T);
    float*    h   = (float*)(wsb + OFF_H);
    float*    tpt = (float*)(wsb + OFF_TPART);

    prep_all<<<dim3(8, 18), 256, 0, stream>>>(memory, key_w, value_w, gate_w,
                                              W2F, W3T, tpt);
    prep_h  <<<1, 512, 0, stream>>>(memory, tpt, h);

    fused_kernel<<<512, 512, 0, stream>>>(x, W2F, W3T, h, gate_b, out);
}